// Round 4
// baseline (2976.159 us; speedup 1.0000x reference)
//
#include <hip/hip_runtime.h>
#include <math.h>

#define N_NODES_C 50000
#define N_GRAPHS_C 64
#define HDIM 128

typedef short bf16x8 __attribute__((ext_vector_type(8)));
typedef short shortx4 __attribute__((ext_vector_type(4)));
typedef float floatx4 __attribute__((ext_vector_type(4)));

// split f32 -> hi (truncated bf16) + lo (bf16 of exact residual)
__device__ inline void cvt_pair(float x, short& h, short& l) {
    union { float f; unsigned u; } a; a.f = x;
    h = (short)(a.u >> 16);
    union { unsigned u; float f; } b; b.u = a.u & 0xFFFF0000u;
    union { float f; unsigned u; } c; c.f = x - b.f;   // exact residual
    l = (short)(c.u >> 16);
}

// ============ split-bf16 MFMA GEMM, register prefetch + XCD tile swizzle ============
#define GBM 128
#define GBN 128
#define GBK 32
#define BKP 40   // padded LDS k-stride (80 B, 16B-aligned, ~2-way banks)

__global__ __launch_bounds__(256, 4) void gemm_mfma_split(
    const float* __restrict__ A, int lda,
    const float* __restrict__ BT, int ldbt,
    const float* __restrict__ bias,
    float* __restrict__ C, int ldc,
    int M, int Ntot, int K,
    int epilogue,                        // 0 none, 1 relu, 2 gated-skip + relu
    const float* __restrict__ skipGate,
    const float* __restrict__ Xprev)
{
    __shared__ __align__(16) short AsH[GBM * BKP];
    __shared__ __align__(16) short AsL[GBM * BKP];
    __shared__ __align__(16) short BsH[GBN * BKP];
    __shared__ __align__(16) short BsL[GBN * BKP];

    // --- XCD-aware swizzle: column-tiles sharing an A row-tile get block
    // indices with equal (mod 8) so they land on the same XCD's L2. ---
    const int tiles_x = gridDim.x, tiles_y = gridDim.y;
    int lin = blockIdx.y * tiles_x + blockIdx.x;
    int S = tiles_y & ~7;
    int full = S * tiles_x;
    int ty, tx;
    if (lin < full) {
        int sr  = lin / (8 * tiles_x);
        int rem = lin - sr * 8 * tiles_x;
        tx = rem >> 3;
        ty = sr * 8 + (rem & 7);
    } else {
        int rem = lin - full;
        ty = S + rem / tiles_x;
        tx = rem - (rem / tiles_x) * tiles_x;
    }
    const long row0 = (long)ty * GBM;
    const long col0 = (long)tx * GBN;

    const int t = threadIdx.x;
    const int lane = t & 63;
    const int wave = t >> 6;
    const int wm = wave & 1, wn = wave >> 1;
    const int quad = lane >> 4, l15 = lane & 15;

    const int srow = t >> 3;          // 0..31
    const int sk = (t & 7) << 2;      // 0,4,..,28

    floatx4 acc[4][4];
    #pragma unroll
    for (int i = 0; i < 4; ++i)
        #pragma unroll
        for (int j = 0; j < 4; ++j)
            acc[i][j] = (floatx4){0.f, 0.f, 0.f, 0.f};

    float4 ra[4], rb[4];
    const float4 fz = {0.f, 0.f, 0.f, 0.f};

    #pragma unroll
    for (int p = 0; p < 4; ++p) {
        int r = p * 32 + srow;
        long gr = row0 + r;
        ra[p] = (gr < M) ? *(const float4*)(A + gr * lda + sk) : fz;
        long gc = col0 + r;
        rb[p] = (gc < Ntot) ? *(const float4*)(BT + gc * ldbt + sk) : fz;
    }

    for (int k0 = 0; k0 < K; k0 += GBK) {
        #pragma unroll
        for (int p = 0; p < 4; ++p) {
            int off = (p * 32 + srow) * BKP + sk;
            short h0, h1, h2, h3, l0, l1, l2, l3;
            cvt_pair(ra[p].x, h0, l0); cvt_pair(ra[p].y, h1, l1);
            cvt_pair(ra[p].z, h2, l2); cvt_pair(ra[p].w, h3, l3);
            *(shortx4*)&AsH[off] = (shortx4){h0, h1, h2, h3};
            *(shortx4*)&AsL[off] = (shortx4){l0, l1, l2, l3};
            cvt_pair(rb[p].x, h0, l0); cvt_pair(rb[p].y, h1, l1);
            cvt_pair(rb[p].z, h2, l2); cvt_pair(rb[p].w, h3, l3);
            *(shortx4*)&BsH[off] = (shortx4){h0, h1, h2, h3};
            *(shortx4*)&BsL[off] = (shortx4){l0, l1, l2, l3};
        }
        __syncthreads();

        if (k0 + GBK < K) {
            int kn = k0 + GBK + sk;
            #pragma unroll
            for (int p = 0; p < 4; ++p) {
                int r = p * 32 + srow;
                long gr = row0 + r;
                ra[p] = (gr < M) ? *(const float4*)(A + gr * lda + kn) : fz;
                long gc = col0 + r;
                rb[p] = (gc < Ntot) ? *(const float4*)(BT + gc * ldbt + kn) : fz;
            }
        }

        bf16x8 aH[4], aL[4], bH[4], bL[4];
        #pragma unroll
        for (int i = 0; i < 4; ++i) {
            int off = (wm * 64 + i * 16 + l15) * BKP + quad * 8;
            aH[i] = *(const bf16x8*)&AsH[off];
            aL[i] = *(const bf16x8*)&AsL[off];
        }
        #pragma unroll
        for (int j = 0; j < 4; ++j) {
            int off = (wn * 64 + j * 16 + l15) * BKP + quad * 8;
            bH[j] = *(const bf16x8*)&BsH[off];
            bL[j] = *(const bf16x8*)&BsL[off];
        }
        #pragma unroll
        for (int i = 0; i < 4; ++i)
            #pragma unroll
            for (int j = 0; j < 4; ++j) {
                acc[i][j] = __builtin_amdgcn_mfma_f32_16x16x32_bf16(aH[i], bH[j], acc[i][j], 0, 0, 0);
                acc[i][j] = __builtin_amdgcn_mfma_f32_16x16x32_bf16(aH[i], bL[j], acc[i][j], 0, 0, 0);
                acc[i][j] = __builtin_amdgcn_mfma_f32_16x16x32_bf16(aL[i], bH[j], acc[i][j], 0, 0, 0);
            }
        __syncthreads();
    }

    float gate = 0.f;
    if (epilogue == 2) gate = 1.f / (1.f + expf(-skipGate[0]));

    #pragma unroll
    for (int i = 0; i < 4; ++i) {
        #pragma unroll
        for (int rr = 0; rr < 4; ++rr) {
            long grow = row0 + wm * 64 + i * 16 + quad * 4 + rr;
            if (grow >= M) continue;
            #pragma unroll
            for (int j = 0; j < 4; ++j) {
                long gcol = col0 + wn * 64 + j * 16 + l15;
                if (gcol >= Ntot) continue;
                float v = acc[i][j][rr];
                if (bias) v += bias[gcol];
                if (epilogue == 2) v = gate * v + (1.f - gate) * Xprev[grow * ldc + gcol];
                if (epilogue >= 1) v = fmaxf(v, 0.f);
                C[grow * ldc + gcol] = v;
            }
        }
    }
}

// ============ build fused transposed weight WbigT[640, F] + bias640 ============
__global__ void build_wbigT(
    const float* __restrict__ Wq, const float* __restrict__ bq,
    const float* __restrict__ Wk, const float* __restrict__ bk,
    const float* __restrict__ Wv, const float* __restrict__ bv,
    const float* __restrict__ arel, const float* __restrict__ mrel,
    float* __restrict__ WT, float* __restrict__ bias, int F)
{
    int idx = blockIdx.x * 256 + threadIdx.x;
    if (idx >= F * 640) return;
    int c = idx / F;
    int f = idx - c * F;
    float w, b = 0.f;
    if (c < 128) {
        w = Wq[(long)f * 128 + c];
        b = bq[c];
    } else {
        int cc = c - 128;
        const float* Wsrc; const float* bsrc; const float* T;
        if (cc < 256) { Wsrc = Wk; bsrc = bk; T = arel; }
        else { cc -= 256; Wsrc = Wv; bsrc = bv; T = mrel; }
        int r = cc >> 7, j = cc & 127, h = j >> 6, e = j & 63;
        const float* Trow = T + ((long)(r * 2 + h) * 4096 + e);
        const float* Wrow = Wsrc + (long)f * 128 + h * 64;
        float s = 0.f;
        for (int d = 0; d < 64; ++d) s += Wrow[d] * Trow[(long)d * 64];
        w = s;
        if (f == 0) {
            float sb = 0.f;
            const float* brow = bsrc + h * 64;
            for (int d = 0; d < 64; ++d) sb += brow[d] * Trow[(long)d * 64];
            b = sb;
        }
    }
    WT[idx] = w;
    if (f == 0) bias[c] = b;
}

__global__ void transpose128(const float* __restrict__ W, float* __restrict__ WT)
{
    int idx = blockIdx.x * 256 + threadIdx.x;   // 16384
    int c = idx >> 7, f = idx & 127;
    WT[idx] = W[f * 128 + c];
}

// ============ edge attention: 16 lanes per (edge,head), float4 gathers,
// both relations in one dispatch (blockIdx.y = r) ============
__global__ __launch_bounds__(256) void edge_attn2_kernel(
    const int* __restrict__ e0p, const int* __restrict__ e1p,
    const float* __restrict__ qkv,
    const float* __restrict__ prel,     // [2][2] (r,h) for this layer
    float* __restrict__ num0, float* __restrict__ den0,
    float* __restrict__ num1, float* __restrict__ den1,
    int E)
{
    int r = blockIdx.y;
    const int* ed = r ? e1p : e0p;
    const int* srcp = ed;
    const int* dstp = ed + E;
    const float* kr = qkv + 128 + r * 128;
    const float* vr = qkv + 384 + r * 128;
    float* num = r ? num1 : num0;
    float* den = r ? den1 : den0;

    int g = blockIdx.x * 16 + (threadIdx.x >> 4);   // group id = (e,h)
    int l = threadIdx.x & 15;
    if (g >= E * 2) return;
    int e = g >> 1;
    int h = g & 1;

    int s = srcp[e];
    int d = dstp[e];
    long bs = (long)s * 640 + h * 64 + l * 4;
    long bd = (long)d * 640 + h * 64 + l * 4;

    float4 q4 = *(const float4*)(qkv + bd);
    float4 k4 = *(const float4*)(kr + bs);
    float p = q4.x * k4.x + q4.y * k4.y + q4.z * k4.z + q4.w * k4.w;
    p += __shfl_xor(p, 1, 16);
    p += __shfl_xor(p, 2, 16);
    p += __shfl_xor(p, 4, 16);
    p += __shfl_xor(p, 8, 16);

    float w = expf(p * prel[r * 2 + h] * 0.125f);   // 1/sqrt(64)

    float4 v4 = *(const float4*)(vr + bs);
    float* np = num + (long)d * 128 + h * 64 + l * 4;
    atomicAdd(np + 0, w * v4.x);
    atomicAdd(np + 1, w * v4.y);
    atomicAdd(np + 2, w * v4.z);
    atomicAdd(np + 3, w * v4.w);
    if (l == 0) atomicAdd(&den[d * 2 + h], w);
}

// ============ fused: out = gelu(num0/den0 + num1/den1) ============
__global__ __launch_bounds__(256) void attn_finalize_kernel(
    const float* __restrict__ num0, const float* __restrict__ den0,
    const float* __restrict__ num1, const float* __restrict__ den1,
    float* __restrict__ out, int total)
{
    int i = blockIdx.x * 256 + threadIdx.x;
    if (i >= total) return;
    int dh = i >> 6;
    float v = num0[i] / (den0[dh] + 1e-16f) + num1[i] / (den1[dh] + 1e-16f);
    out[i] = 0.5f * v * (1.f + erff(v * 0.70710678118654752f));
}

// ============ f32 vector GEMM kept for tiny MLP ============
#define BM 64
#define BN 64
#define BK 16
__global__ __launch_bounds__(256) void gemm_bias_kernel(
    const float* __restrict__ A, int lda,
    const float* __restrict__ B, int ldb,
    const float* __restrict__ bias,
    float* __restrict__ C, int ldc,
    int M, int K, int epilogue)
{
    __shared__ float As[BK][BM + 4];
    __shared__ float Bs[BK][BN + 4];
    const int t = threadIdx.x;
    const int row0 = blockIdx.y * BM;
    const int col0 = blockIdx.x * BN;
    const int tm = (t >> 4) << 2;
    const int tn = (t & 15) << 2;
    float acc[4][4] = {};
    for (int k0 = 0; k0 < K; k0 += BK) {
        #pragma unroll
        for (int i = 0; i < 4; ++i) {
            int idx = t + i * 256;
            int m = idx >> 4, kk = idx & 15;
            int gm = row0 + m;
            As[kk][m] = (gm < M) ? A[(long)gm * lda + (k0 + kk)] : 0.f;
        }
        #pragma unroll
        for (int i = 0; i < 4; ++i) {
            int idx = t + i * 256;
            int kk = idx >> 6, n = idx & 63;
            Bs[kk][n] = B[(long)(k0 + kk) * ldb + (col0 + n)];
        }
        __syncthreads();
        #pragma unroll
        for (int kk = 0; kk < BK; ++kk) {
            float a[4], b[4];
            #pragma unroll
            for (int i = 0; i < 4; ++i) a[i] = As[kk][tm + i];
            #pragma unroll
            for (int j = 0; j < 4; ++j) b[j] = Bs[kk][tn + j];
            #pragma unroll
            for (int i = 0; i < 4; ++i)
                #pragma unroll
                for (int j = 0; j < 4; ++j)
                    acc[i][j] = fmaf(a[i], b[j], acc[i][j]);
        }
        __syncthreads();
    }
    #pragma unroll
    for (int i = 0; i < 4; ++i) {
        int gm = row0 + tm + i;
        if (gm >= M) continue;
        #pragma unroll
        for (int j = 0; j < 4; ++j) {
            int gn = col0 + tn + j;
            float v = acc[i][j];
            if (bias) v += bias[gn];
            if (epilogue >= 1) v = fmaxf(v, 0.f);
            C[(long)gm * ldc + gn] = v;
        }
    }
}

// ============ pooling ============
__device__ inline int lower_bound_i(const int* __restrict__ a, int n, int v)
{
    int lo = 0, hi = n;
    while (lo < hi) { int mid = (lo + hi) >> 1; if (a[mid] < v) lo = mid + 1; else hi = mid; }
    return lo;
}

__global__ void pool_kernel(const float* __restrict__ h, const int* __restrict__ batch,
                            float* __restrict__ s, int N)
{
    int g = blockIdx.x, part = blockIdx.y, c = threadIdx.x;
    int start = lower_bound_i(batch, N, g);
    int end = lower_bound_i(batch, N, g + 1);
    int cnt = end - start, parts = gridDim.y;
    int chunk = (cnt + parts - 1) / parts;
    int a = start + part * chunk;
    int b = a + chunk; if (b > end) b = end;
    if (a >= b) return;
    float sum = 0.f;
    for (int n = a; n < b; ++n) sum += h[(long)n * HDIM + c];
    atomicAdd(&s[g * HDIM + c], sum);
}

__global__ void pool_finalize(const float* __restrict__ s, const int* __restrict__ batch,
                              float* __restrict__ g_out, int N)
{
    int g = blockIdx.x, c = threadIdx.x;
    int start = lower_bound_i(batch, N, g);
    int end = lower_bound_i(batch, N, g + 1);
    float cnt = (float)((end - start) > 1 ? (end - start) : 1);
    g_out[g * HDIM + c] = s[g * HDIM + c] / cnt;
}

// ============ host ============
extern "C" void kernel_launch(void* const* d_in, const int* in_sizes, int n_in,
                              void* d_out, int out_size, void* d_ws, size_t ws_size,
                              hipStream_t stream)
{
    const float* x      = (const float*)d_in[0];
    const int*   e0     = (const int*)d_in[1];
    const int*   e1     = (const int*)d_in[2];
    const int*   batch  = (const int*)d_in[3];
    const float* W_k1   = (const float*)d_in[4];
    const float* W_q1   = (const float*)d_in[5];
    const float* W_v1   = (const float*)d_in[6];
    const float* a_rel1 = (const float*)d_in[7];
    const float* m_rel1 = (const float*)d_in[8];
    const float* W_a1   = (const float*)d_in[9];
    const float* W_k23  = (const float*)d_in[10];
    const float* W_q23  = (const float*)d_in[11];
    const float* W_v23  = (const float*)d_in[12];
    const float* a_rel23= (const float*)d_in[13];
    const float* m_rel23= (const float*)d_in[14];
    const float* W_a23  = (const float*)d_in[15];
    const float* W_m1   = (const float*)d_in[16];
    const float* W_m2   = (const float*)d_in[17];
    const float* b_k1   = (const float*)d_in[18];
    const float* b_q1   = (const float*)d_in[19];
    const float* b_v1   = (const float*)d_in[20];
    const float* b_a1   = (const float*)d_in[21];
    const float* b_k23  = (const float*)d_in[22];
    const float* b_q23  = (const float*)d_in[23];
    const float* b_v23  = (const float*)d_in[24];
    const float* b_a23  = (const float*)d_in[25];
    const float* skip23 = (const float*)d_in[26];
    const float* b_m1   = (const float*)d_in[27];
    const float* b_m2   = (const float*)d_in[28];
    const float* p_rel1 = (const float*)d_in[29];
    const float* p_rel23= (const float*)d_in[30];

    const int N = N_NODES_C;
    const int E = in_sizes[1] / 2;
    const int F = in_sizes[0] / N;            // 512
    const long NN = (long)N * HDIM;           // 6.4M

    float* ws   = (float*)d_ws;
    float* QKV  = ws;                          // 50000*640
    float* ACC  = QKV + (long)N * 640;         // NN  (NUM1, then gelu output)
    float* NUM  = ACC + NN;                    // NN  (NUM0; start aliases WT)
    float* H1   = NUM + NN;                    // NN
    float* H2   = H1 + NN;                     // NN
    float* DEN  = H2 + NN;                     // N*2 (DEN0)
    float* S    = DEN + (long)N * 2;
    float* GM   = S + N_GRAPHS_C * HDIM;
    float* M1   = GM + N_GRAPHS_C * HDIM;
    float* WT   = NUM;                         // 640*F, dead before NUM0 used
    float* B640 = NUM + 400000;                // 640, same lifetime as WT
    float* WaT  = QKV;                         // 16384, QKV dead by out-proj time
    size_t needed = (size_t)((long)N * 640 + 4 * NN + (long)N * 2 + 3L * N_GRAPHS_C * HDIM) * sizeof(float);
    if (ws_size < needed) return;

    auto mfma_gemm = [&](const float* A, int lda, const float* BTp, int ldbt,
                         const float* bias, float* Cp, int ldc, int M, int Nc, int K,
                         int epi, const float* gate, const float* xprev) {
        dim3 grid(Nc / GBN, (M + GBM - 1) / GBM);
        gemm_mfma_split<<<grid, 256, 0, stream>>>(A, lda, BTp, ldbt, bias, Cp, ldc,
                                                  M, Nc, K, epi, gate, xprev);
    };

    auto run_layer = [&](const float* hin, int Fin,
                         const float* Wk, const float* bk,
                         const float* Wq, const float* bq,
                         const float* Wv, const float* bv,
                         const float* arel, const float* mrel, const float* prel,
                         const float* Wa, const float* ba,
                         const float* gate, float* hout) {
        int tot = Fin * 640;
        build_wbigT<<<(tot + 255) / 256, 256, 0, stream>>>(Wq, bq, Wk, bk, Wv, bv,
                                                           arel, mrel, WT, B640, Fin);
        mfma_gemm(hin, Fin, WT, Fin, B640, QKV, 640, N, 640, Fin, 0, nullptr, nullptr);

        float* NUM0 = NUM;  float* DEN0 = DEN;
        float* NUM1 = ACC;  float* DEN1 = hout;   // hout written only at out-proj
        // ACC and NUM are contiguous -> single memset covers NUM1 then NUM0
        hipMemsetAsync(ACC, 0, 2 * NN * sizeof(float), stream);
        hipMemsetAsync(DEN0, 0, (size_t)N * 2 * sizeof(float), stream);
        hipMemsetAsync(DEN1, 0, (size_t)N * 2 * sizeof(float), stream);

        int groups = E * 2;
        dim3 eg((groups + 15) / 16, 2);
        edge_attn2_kernel<<<eg, 256, 0, stream>>>(e0, e1, QKV, prel,
                                                  NUM0, DEN0, NUM1, DEN1, E);

        attn_finalize_kernel<<<(int)((NN + 255) / 256), 256, 0, stream>>>(
            NUM0, DEN0, NUM1, DEN1, ACC, (int)NN);

        transpose128<<<64, 256, 0, stream>>>(Wa, WaT);
        mfma_gemm(ACC, 128, WaT, 128, ba, hout, 128, N, 128, 128,
                  gate ? 2 : 1, gate, hin);
    };

    run_layer(x, F, W_k1, b_k1, W_q1, b_q1, W_v1, b_v1,
              a_rel1, m_rel1, p_rel1, W_a1, b_a1, nullptr, H1);
    run_layer(H1, HDIM, W_k23, b_k23, W_q23, b_q23, W_v23, b_v23,
              a_rel23, m_rel23, p_rel23, W_a23, b_a23, skip23, H2);
    run_layer(H2, HDIM, W_k23 + 16384, b_k23 + 128, W_q23 + 16384, b_q23 + 128,
              W_v23 + 16384, b_v23 + 128, a_rel23 + 16384, m_rel23 + 16384,
              p_rel23 + 4, W_a23 + 16384, b_a23 + 128, skip23 + 1, H1);

    hipMemsetAsync(S, 0, (size_t)N_GRAPHS_C * HDIM * sizeof(float), stream);
    dim3 pg(N_GRAPHS_C, 8);
    pool_kernel<<<pg, HDIM, 0, stream>>>(H1, batch, S, N);
    pool_finalize<<<N_GRAPHS_C, HDIM, 0, stream>>>(S, batch, GM, N);

    {
        dim3 g1(128 / BN, 1);
        gemm_bias_kernel<<<g1, 256, 0, stream>>>(GM, 128, W_m1, 128, b_m1, M1, 128,
                                                 N_GRAPHS_C, 128, 1);
        dim3 g2(256 / BN, 1);
        gemm_bias_kernel<<<g2, 256, 0, stream>>>(M1, 128, W_m2, 256, b_m2,
                                                 (float*)d_out, 256, N_GRAPHS_C, 128, 0);
    }
}

// Round 5
// 1806.078 us; speedup vs baseline: 1.6479x; 1.6479x over previous
//
#include <hip/hip_runtime.h>
#include <math.h>

#define N_NODES_C 50000
#define N_GRAPHS_C 64
#define HDIM 128

typedef short bf16x8 __attribute__((ext_vector_type(8)));
typedef short shortx4 __attribute__((ext_vector_type(4)));
typedef float floatx4 __attribute__((ext_vector_type(4)));

// split f32 -> hi (truncated bf16) + lo (bf16 of exact residual)
__device__ inline void cvt_pair(float x, short& h, short& l) {
    union { float f; unsigned u; } a; a.f = x;
    h = (short)(a.u >> 16);
    union { unsigned u; float f; } b; b.u = a.u & 0xFFFF0000u;
    union { float f; unsigned u; } c; c.f = x - b.f;   // exact residual
    l = (short)(c.u >> 16);
}

// ============ split-bf16 MFMA GEMM, register prefetch + XCD tile swizzle ============
#define GBM 128
#define GBN 128
#define GBK 32
#define BKP 40   // padded LDS k-stride (80 B, 16B-aligned, ~2-way banks)

__global__ __launch_bounds__(256, 4) void gemm_mfma_split(
    const float* __restrict__ A, int lda,
    const float* __restrict__ BT, int ldbt,
    const float* __restrict__ bias,
    float* __restrict__ C, int ldc,
    int M, int Ntot, int K,
    int epilogue,                        // 0 none, 1 relu, 2 gated-skip + relu
    const float* __restrict__ skipGate,
    const float* __restrict__ Xprev)
{
    __shared__ __align__(16) short AsH[GBM * BKP];
    __shared__ __align__(16) short AsL[GBM * BKP];
    __shared__ __align__(16) short BsH[GBN * BKP];
    __shared__ __align__(16) short BsL[GBN * BKP];

    // XCD-aware swizzle: column-tiles sharing an A row-tile land on one XCD's L2
    const int tiles_x = gridDim.x, tiles_y = gridDim.y;
    int lin = blockIdx.y * tiles_x + blockIdx.x;
    int S = tiles_y & ~7;
    int full = S * tiles_x;
    int ty, tx;
    if (lin < full) {
        int sr  = lin / (8 * tiles_x);
        int rem = lin - sr * 8 * tiles_x;
        tx = rem >> 3;
        ty = sr * 8 + (rem & 7);
    } else {
        int rem = lin - full;
        ty = S + rem / tiles_x;
        tx = rem - (rem / tiles_x) * tiles_x;
    }
    const long row0 = (long)ty * GBM;
    const long col0 = (long)tx * GBN;

    const int t = threadIdx.x;
    const int lane = t & 63;
    const int wave = t >> 6;
    const int wm = wave & 1, wn = wave >> 1;
    const int quad = lane >> 4, l15 = lane & 15;

    const int srow = t >> 3;          // 0..31
    const int sk = (t & 7) << 2;      // 0,4,..,28

    floatx4 acc[4][4];
    #pragma unroll
    for (int i = 0; i < 4; ++i)
        #pragma unroll
        for (int j = 0; j < 4; ++j)
            acc[i][j] = (floatx4){0.f, 0.f, 0.f, 0.f};

    float4 ra[4], rb[4];
    const float4 fz = {0.f, 0.f, 0.f, 0.f};

    #pragma unroll
    for (int p = 0; p < 4; ++p) {
        int r = p * 32 + srow;
        long gr = row0 + r;
        ra[p] = (gr < M) ? *(const float4*)(A + gr * lda + sk) : fz;
        long gc = col0 + r;
        rb[p] = (gc < Ntot) ? *(const float4*)(BT + gc * ldbt + sk) : fz;
    }

    for (int k0 = 0; k0 < K; k0 += GBK) {
        #pragma unroll
        for (int p = 0; p < 4; ++p) {
            int off = (p * 32 + srow) * BKP + sk;
            short h0, h1, h2, h3, l0, l1, l2, l3;
            cvt_pair(ra[p].x, h0, l0); cvt_pair(ra[p].y, h1, l1);
            cvt_pair(ra[p].z, h2, l2); cvt_pair(ra[p].w, h3, l3);
            *(shortx4*)&AsH[off] = (shortx4){h0, h1, h2, h3};
            *(shortx4*)&AsL[off] = (shortx4){l0, l1, l2, l3};
            cvt_pair(rb[p].x, h0, l0); cvt_pair(rb[p].y, h1, l1);
            cvt_pair(rb[p].z, h2, l2); cvt_pair(rb[p].w, h3, l3);
            *(shortx4*)&BsH[off] = (shortx4){h0, h1, h2, h3};
            *(shortx4*)&BsL[off] = (shortx4){l0, l1, l2, l3};
        }
        __syncthreads();

        if (k0 + GBK < K) {
            int kn = k0 + GBK + sk;
            #pragma unroll
            for (int p = 0; p < 4; ++p) {
                int r = p * 32 + srow;
                long gr = row0 + r;
                ra[p] = (gr < M) ? *(const float4*)(A + gr * lda + kn) : fz;
                long gc = col0 + r;
                rb[p] = (gc < Ntot) ? *(const float4*)(BT + gc * ldbt + kn) : fz;
            }
        }

        bf16x8 aH[4], aL[4], bH[4], bL[4];
        #pragma unroll
        for (int i = 0; i < 4; ++i) {
            int off = (wm * 64 + i * 16 + l15) * BKP + quad * 8;
            aH[i] = *(const bf16x8*)&AsH[off];
            aL[i] = *(const bf16x8*)&AsL[off];
        }
        #pragma unroll
        for (int j = 0; j < 4; ++j) {
            int off = (wn * 64 + j * 16 + l15) * BKP + quad * 8;
            bH[j] = *(const bf16x8*)&BsH[off];
            bL[j] = *(const bf16x8*)&BsL[off];
        }
        #pragma unroll
        for (int i = 0; i < 4; ++i)
            #pragma unroll
            for (int j = 0; j < 4; ++j) {
                acc[i][j] = __builtin_amdgcn_mfma_f32_16x16x32_bf16(aH[i], bH[j], acc[i][j], 0, 0, 0);
                acc[i][j] = __builtin_amdgcn_mfma_f32_16x16x32_bf16(aH[i], bL[j], acc[i][j], 0, 0, 0);
                acc[i][j] = __builtin_amdgcn_mfma_f32_16x16x32_bf16(aL[i], bH[j], acc[i][j], 0, 0, 0);
            }
        __syncthreads();
    }

    float gate = 0.f;
    if (epilogue == 2) gate = 1.f / (1.f + expf(-skipGate[0]));

    #pragma unroll
    for (int i = 0; i < 4; ++i) {
        #pragma unroll
        for (int rr = 0; rr < 4; ++rr) {
            long grow = row0 + wm * 64 + i * 16 + quad * 4 + rr;
            if (grow >= M) continue;
            #pragma unroll
            for (int j = 0; j < 4; ++j) {
                long gcol = col0 + wn * 64 + j * 16 + l15;
                if (gcol >= Ntot) continue;
                float v = acc[i][j][rr];
                if (bias) v += bias[gcol];
                if (epilogue == 2) v = gate * v + (1.f - gate) * Xprev[grow * ldc + gcol];
                if (epilogue >= 1) v = fmaxf(v, 0.f);
                C[grow * ldc + gcol] = v;
            }
        }
    }
}

// ============ build fused transposed weight WbigT[640, F] + bias640 ============
__global__ void build_wbigT(
    const float* __restrict__ Wq, const float* __restrict__ bq,
    const float* __restrict__ Wk, const float* __restrict__ bk,
    const float* __restrict__ Wv, const float* __restrict__ bv,
    const float* __restrict__ arel, const float* __restrict__ mrel,
    float* __restrict__ WT, float* __restrict__ bias, int F)
{
    int idx = blockIdx.x * 256 + threadIdx.x;
    if (idx >= F * 640) return;
    int c = idx / F;
    int f = idx - c * F;
    float w, b = 0.f;
    if (c < 128) {
        w = Wq[(long)f * 128 + c];
        b = bq[c];
    } else {
        int cc = c - 128;
        const float* Wsrc; const float* bsrc; const float* T;
        if (cc < 256) { Wsrc = Wk; bsrc = bk; T = arel; }
        else { cc -= 256; Wsrc = Wv; bsrc = bv; T = mrel; }
        int r = cc >> 7, j = cc & 127, h = j >> 6, e = j & 63;
        const float* Trow = T + ((long)(r * 2 + h) * 4096 + e);
        const float* Wrow = Wsrc + (long)f * 128 + h * 64;
        float s = 0.f;
        for (int d = 0; d < 64; ++d) s += Wrow[d] * Trow[(long)d * 64];
        w = s;
        if (f == 0) {
            float sb = 0.f;
            const float* brow = bsrc + h * 64;
            for (int d = 0; d < 64; ++d) sb += brow[d] * Trow[(long)d * 64];
            b = sb;
        }
    }
    WT[idx] = w;
    if (f == 0) bias[c] = b;
}

__global__ void transpose128(const float* __restrict__ W, float* __restrict__ WT)
{
    int idx = blockIdx.x * 256 + threadIdx.x;   // 16384
    int c = idx >> 7, f = idx & 127;
    WT[idx] = W[f * 128 + c];
}

// ============ CSR build (edges fixed across layers: built once) ============
__global__ void csr_count_kernel(const int* __restrict__ dst, int* __restrict__ counts, int E)
{
    int e = blockIdx.x * 256 + threadIdx.x;
    if (e < E) atomicAdd(&counts[dst[e]], 1);
}

__global__ __launch_bounds__(1024) void csr_scan_kernel(
    const int* __restrict__ counts, int* __restrict__ offsets,
    int* __restrict__ cursor, int N, int E)
{
    __shared__ int part[1024];
    int t = threadIdx.x;
    int chunk = (N + 1023) / 1024;
    int a = t * chunk, b = a + chunk; if (b > N) b = N;
    int s = 0;
    for (int i = a; i < b; ++i) s += counts[i];
    part[t] = s;
    __syncthreads();
    for (int off = 1; off < 1024; off <<= 1) {
        int v = (t >= off) ? part[t - off] : 0;
        __syncthreads();
        if (t >= off) part[t] += v;
        __syncthreads();
    }
    int p = (t == 0) ? 0 : part[t - 1];
    for (int i = a; i < b; ++i) {
        offsets[i] = p; cursor[i] = p; p += counts[i];
    }
    if (t == 1023) offsets[N] = E;
}

__global__ void csr_fill_kernel(const int* __restrict__ src, const int* __restrict__ dst,
                                int* __restrict__ cursor, int* __restrict__ ssrc, int E)
{
    int e = blockIdx.x * 256 + threadIdx.x;
    if (e >= E) return;
    int pos = atomicAdd(&cursor[dst[e]], 1);
    ssrc[pos] = src[e];
}

// ============ node attention: one wave per (node, head), CSR walk, no atomics ====
// out[d,h,:] = gelu( sum_r  sum_e w_e * v_r[src_e] / sum_e w_e ), w = exp(qk*p/8)
__global__ __launch_bounds__(256) void node_attn_kernel(
    const float* __restrict__ qkv,
    const int* __restrict__ off0, const int* __restrict__ ss0,
    const int* __restrict__ off1, const int* __restrict__ ss1,
    const float* __restrict__ prel,     // [2][2] (r,h)
    float* __restrict__ out, int N)
{
    int wid = blockIdx.x * 4 + (threadIdx.x >> 6);
    int lane = threadIdx.x & 63;
    int d = wid >> 1;
    int h = wid & 1;
    if (d >= N) return;

    float q = qkv[(long)d * 640 + h * 64 + lane];
    float acc = 0.f;

    #pragma unroll
    for (int r = 0; r < 2; ++r) {
        const int* off = r ? off1 : off0;
        const int* ss  = r ? ss1  : ss0;
        const float* kr = qkv + 128 + r * 128 + h * 64 + lane;
        const float* vr = qkv + 384 + r * 128 + h * 64 + lane;
        float pr = prel[r * 2 + h] * 0.125f;   // includes 1/sqrt(64)
        int a = off[d], b = off[d + 1];
        float num = 0.f, den = 0.f;
        for (int i = a; i < b; ++i) {
            long s = (long)ss[i] * 640;
            float k = kr[s];
            float v = vr[s];
            float p = q * k;
            #pragma unroll
            for (int o = 32; o; o >>= 1) p += __shfl_xor(p, o, 64);
            float w = expf(p * pr);
            den += w;
            num = fmaf(w, v, num);
        }
        acc += num / (den + 1e-16f);
    }

    out[(long)d * 128 + h * 64 + lane] =
        0.5f * acc * (1.f + erff(acc * 0.70710678118654752f));
}

// ============ f32 vector GEMM kept for tiny MLP ============
#define BM 64
#define BN 64
#define BK 16
__global__ __launch_bounds__(256) void gemm_bias_kernel(
    const float* __restrict__ A, int lda,
    const float* __restrict__ B, int ldb,
    const float* __restrict__ bias,
    float* __restrict__ C, int ldc,
    int M, int K, int epilogue)
{
    __shared__ float As[BK][BM + 4];
    __shared__ float Bs[BK][BN + 4];
    const int t = threadIdx.x;
    const int row0 = blockIdx.y * BM;
    const int col0 = blockIdx.x * BN;
    const int tm = (t >> 4) << 2;
    const int tn = (t & 15) << 2;
    float acc[4][4] = {};
    for (int k0 = 0; k0 < K; k0 += BK) {
        #pragma unroll
        for (int i = 0; i < 4; ++i) {
            int idx = t + i * 256;
            int m = idx >> 4, kk = idx & 15;
            int gm = row0 + m;
            As[kk][m] = (gm < M) ? A[(long)gm * lda + (k0 + kk)] : 0.f;
        }
        #pragma unroll
        for (int i = 0; i < 4; ++i) {
            int idx = t + i * 256;
            int kk = idx >> 6, n = idx & 63;
            Bs[kk][n] = B[(long)(k0 + kk) * ldb + (col0 + n)];
        }
        __syncthreads();
        #pragma unroll
        for (int kk = 0; kk < BK; ++kk) {
            float a[4], b[4];
            #pragma unroll
            for (int i = 0; i < 4; ++i) a[i] = As[kk][tm + i];
            #pragma unroll
            for (int j = 0; j < 4; ++j) b[j] = Bs[kk][tn + j];
            #pragma unroll
            for (int i = 0; i < 4; ++i)
                #pragma unroll
                for (int j = 0; j < 4; ++j)
                    acc[i][j] = fmaf(a[i], b[j], acc[i][j]);
        }
        __syncthreads();
    }
    #pragma unroll
    for (int i = 0; i < 4; ++i) {
        int gm = row0 + tm + i;
        if (gm >= M) continue;
        #pragma unroll
        for (int j = 0; j < 4; ++j) {
            int gn = col0 + tn + j;
            float v = acc[i][j];
            if (bias) v += bias[gn];
            if (epilogue >= 1) v = fmaxf(v, 0.f);
            C[(long)gm * ldc + gn] = v;
        }
    }
}

// ============ pooling ============
__device__ inline int lower_bound_i(const int* __restrict__ a, int n, int v)
{
    int lo = 0, hi = n;
    while (lo < hi) { int mid = (lo + hi) >> 1; if (a[mid] < v) lo = mid + 1; else hi = mid; }
    return lo;
}

__global__ void pool_kernel(const float* __restrict__ h, const int* __restrict__ batch,
                            float* __restrict__ s, int N)
{
    int g = blockIdx.x, part = blockIdx.y, c = threadIdx.x;
    int start = lower_bound_i(batch, N, g);
    int end = lower_bound_i(batch, N, g + 1);
    int cnt = end - start, parts = gridDim.y;
    int chunk = (cnt + parts - 1) / parts;
    int a = start + part * chunk;
    int b = a + chunk; if (b > end) b = end;
    if (a >= b) return;
    float sum = 0.f;
    for (int n = a; n < b; ++n) sum += h[(long)n * HDIM + c];
    atomicAdd(&s[g * HDIM + c], sum);
}

__global__ void pool_finalize(const float* __restrict__ s, const int* __restrict__ batch,
                              float* __restrict__ g_out, int N)
{
    int g = blockIdx.x, c = threadIdx.x;
    int start = lower_bound_i(batch, N, g);
    int end = lower_bound_i(batch, N, g + 1);
    float cnt = (float)((end - start) > 1 ? (end - start) : 1);
    g_out[g * HDIM + c] = s[g * HDIM + c] / cnt;
}

// ============ host ============
extern "C" void kernel_launch(void* const* d_in, const int* in_sizes, int n_in,
                              void* d_out, int out_size, void* d_ws, size_t ws_size,
                              hipStream_t stream)
{
    const float* x      = (const float*)d_in[0];
    const int*   e0     = (const int*)d_in[1];
    const int*   e1     = (const int*)d_in[2];
    const int*   batch  = (const int*)d_in[3];
    const float* W_k1   = (const float*)d_in[4];
    const float* W_q1   = (const float*)d_in[5];
    const float* W_v1   = (const float*)d_in[6];
    const float* a_rel1 = (const float*)d_in[7];
    const float* m_rel1 = (const float*)d_in[8];
    const float* W_a1   = (const float*)d_in[9];
    const float* W_k23  = (const float*)d_in[10];
    const float* W_q23  = (const float*)d_in[11];
    const float* W_v23  = (const float*)d_in[12];
    const float* a_rel23= (const float*)d_in[13];
    const float* m_rel23= (const float*)d_in[14];
    const float* W_a23  = (const float*)d_in[15];
    const float* W_m1   = (const float*)d_in[16];
    const float* W_m2   = (const float*)d_in[17];
    const float* b_k1   = (const float*)d_in[18];
    const float* b_q1   = (const float*)d_in[19];
    const float* b_v1   = (const float*)d_in[20];
    const float* b_a1   = (const float*)d_in[21];
    const float* b_k23  = (const float*)d_in[22];
    const float* b_q23  = (const float*)d_in[23];
    const float* b_v23  = (const float*)d_in[24];
    const float* b_a23  = (const float*)d_in[25];
    const float* skip23 = (const float*)d_in[26];
    const float* b_m1   = (const float*)d_in[27];
    const float* b_m2   = (const float*)d_in[28];
    const float* p_rel1 = (const float*)d_in[29];
    const float* p_rel23= (const float*)d_in[30];

    const int N = N_NODES_C;
    const int E = in_sizes[1] / 2;
    const int F = in_sizes[0] / N;            // 512
    const long NN = (long)N * HDIM;           // 6.4M

    // ---- workspace layout (no aliasing) ----
    float* ws   = (float*)d_ws;
    float* QKV  = ws;                          // N*640
    float* ACC  = QKV + (long)N * 640;         // NN (gelu(attention) output)
    float* H1   = ACC + NN;                    // NN
    float* H2   = H1 + NN;                     // NN
    float* WT   = H2 + NN;                     // 640*512 max
    float* B640 = WT + 640 * 512;              // 640
    float* S    = B640 + 640;                  // 64*128
    float* GM   = S + N_GRAPHS_C * HDIM;
    float* M1   = GM + N_GRAPHS_C * HDIM;
    int*   ip   = (int*)(M1 + N_GRAPHS_C * HDIM);
    int*   off0 = ip;                          // N+1
    int*   ss0  = off0 + (N + 1);              // E
    int*   off1 = ss0 + E;                     // N+1
    int*   ss1  = off1 + (N + 1);              // E
    int*   counts = ss1 + E;                   // N
    int*   cursor = counts + N;                // N
    size_t needed = (size_t)((char*)(cursor + N) - (char*)d_ws);
    if (ws_size < needed) return;

    // ---- build CSR for both relations (once; edges fixed across layers) ----
    {
        int eb = (E + 255) / 256;
        hipMemsetAsync(counts, 0, (size_t)N * sizeof(int), stream);
        csr_count_kernel<<<eb, 256, 0, stream>>>(e0 + E, counts, E);
        csr_scan_kernel<<<1, 1024, 0, stream>>>(counts, off0, cursor, N, E);
        csr_fill_kernel<<<eb, 256, 0, stream>>>(e0, e0 + E, cursor, ss0, E);

        hipMemsetAsync(counts, 0, (size_t)N * sizeof(int), stream);
        csr_count_kernel<<<eb, 256, 0, stream>>>(e1 + E, counts, E);
        csr_scan_kernel<<<1, 1024, 0, stream>>>(counts, off1, cursor, N, E);
        csr_fill_kernel<<<eb, 256, 0, stream>>>(e1, e1 + E, cursor, ss1, E);
    }

    auto mfma_gemm = [&](const float* A, int lda, const float* BTp, int ldbt,
                         const float* bias, float* Cp, int ldc, int M, int Nc, int K,
                         int epi, const float* gate, const float* xprev) {
        dim3 grid(Nc / GBN, (M + GBM - 1) / GBM);
        gemm_mfma_split<<<grid, 256, 0, stream>>>(A, lda, BTp, ldbt, bias, Cp, ldc,
                                                  M, Nc, K, epi, gate, xprev);
    };

    auto run_layer = [&](const float* hin, int Fin,
                         const float* Wk, const float* bk,
                         const float* Wq, const float* bq,
                         const float* Wv, const float* bv,
                         const float* arel, const float* mrel, const float* prel,
                         const float* Wa, const float* ba,
                         const float* gate, float* hout) {
        int tot = Fin * 640;
        build_wbigT<<<(tot + 255) / 256, 256, 0, stream>>>(Wq, bq, Wk, bk, Wv, bv,
                                                           arel, mrel, WT, B640, Fin);
        mfma_gemm(hin, Fin, WT, Fin, B640, QKV, 640, N, 640, Fin, 0, nullptr, nullptr);

        // fused attention + softmax + relation-sum + gelu, no atomics
        int waves = N * 2;
        node_attn_kernel<<<(waves + 3) / 4, 256, 0, stream>>>(
            QKV, off0, ss0, off1, ss1, prel, ACC, N);

        transpose128<<<64, 256, 0, stream>>>(Wa, WT);
        mfma_gemm(ACC, 128, WT, 128, ba, hout, 128, N, 128, 128,
                  gate ? 2 : 1, gate, hin);
    };

    run_layer(x, F, W_k1, b_k1, W_q1, b_q1, W_v1, b_v1,
              a_rel1, m_rel1, p_rel1, W_a1, b_a1, nullptr, H1);
    run_layer(H1, HDIM, W_k23, b_k23, W_q23, b_q23, W_v23, b_v23,
              a_rel23, m_rel23, p_rel23, W_a23, b_a23, skip23, H2);
    run_layer(H2, HDIM, W_k23 + 16384, b_k23 + 128, W_q23 + 16384, b_q23 + 128,
              W_v23 + 16384, b_v23 + 128, a_rel23 + 16384, m_rel23 + 16384,
              p_rel23 + 4, W_a23 + 16384, b_a23 + 128, skip23 + 1, H1);

    hipMemsetAsync(S, 0, (size_t)N_GRAPHS_C * HDIM * sizeof(float), stream);
    dim3 pg(N_GRAPHS_C, 8);
    pool_kernel<<<pg, HDIM, 0, stream>>>(H1, batch, S, N);
    pool_finalize<<<N_GRAPHS_C, HDIM, 0, stream>>>(S, batch, GM, N);

    {
        dim3 g1(128 / BN, 1);
        gemm_bias_kernel<<<g1, 256, 0, stream>>>(GM, 128, W_m1, 128, b_m1, M1, 128,
                                                 N_GRAPHS_C, 128, 1);
        dim3 g2(256 / BN, 1);
        gemm_bias_kernel<<<g2, 256, 0, stream>>>(M1, 128, W_m2, 256, b_m2,
                                                 (float*)d_out, 256, N_GRAPHS_C, 128, 0);
    }
}

// Round 6
// 1228.036 us; speedup vs baseline: 2.4235x; 1.4707x over previous
//
#include <hip/hip_runtime.h>
#include <math.h>

#define N_NODES_C 50000
#define N_GRAPHS_C 64
#define HDIM 128

typedef short bf16x8 __attribute__((ext_vector_type(8)));
typedef short shortx4 __attribute__((ext_vector_type(4)));
typedef float floatx4 __attribute__((ext_vector_type(4)));

// split f32 -> hi (truncated bf16) + lo (bf16 of exact residual)
__device__ inline void cvt_pair(float x, short& h, short& l) {
    union { float f; unsigned u; } a; a.f = x;
    h = (short)(a.u >> 16);
    union { unsigned u; float f; } b; b.u = a.u & 0xFFFF0000u;
    union { float f; unsigned u; } c; c.f = x - b.f;   // exact residual
    l = (short)(c.u >> 16);
}

// ============ split-bf16 MFMA GEMM, register prefetch + XCD tile swizzle ============
#define GBM 128
#define GBN 128
#define GBK 32
#define BKP 40   // padded LDS k-stride (80 B, 16B-aligned, ~2-way banks)

// NOTE: (256,2) NOT (256,4) — the latter caps VGPR at 64 and spills the
// 64-AGPR accumulator to scratch (R5: WRITE 133MB->1.3GB, 162->520us).
__global__ __launch_bounds__(256, 2) void gemm_mfma_split(
    const float* __restrict__ A, int lda,
    const float* __restrict__ BT, int ldbt,
    const float* __restrict__ bias,
    float* __restrict__ C, int ldc,
    int M, int Ntot, int K,
    int epilogue,                        // 0 none, 1 relu, 2 gated-skip + relu
    const float* __restrict__ skipGate,
    const float* __restrict__ Xprev)
{
    __shared__ __align__(16) short AsH[GBM * BKP];
    __shared__ __align__(16) short AsL[GBM * BKP];
    __shared__ __align__(16) short BsH[GBN * BKP];
    __shared__ __align__(16) short BsL[GBN * BKP];

    // XCD-aware swizzle: column-tiles sharing an A row-tile land on one XCD's L2
    const int tiles_x = gridDim.x, tiles_y = gridDim.y;
    int lin = blockIdx.y * tiles_x + blockIdx.x;
    int S = tiles_y & ~7;
    int full = S * tiles_x;
    int ty, tx;
    if (lin < full) {
        int sr  = lin / (8 * tiles_x);
        int rem = lin - sr * 8 * tiles_x;
        tx = rem >> 3;
        ty = sr * 8 + (rem & 7);
    } else {
        int rem = lin - full;
        ty = S + rem / tiles_x;
        tx = rem - (rem / tiles_x) * tiles_x;
    }
    const long row0 = (long)ty * GBM;
    const long col0 = (long)tx * GBN;

    const int t = threadIdx.x;
    const int lane = t & 63;
    const int wave = t >> 6;
    const int wm = wave & 1, wn = wave >> 1;
    const int quad = lane >> 4, l15 = lane & 15;

    const int srow = t >> 3;          // 0..31
    const int sk = (t & 7) << 2;      // 0,4,..,28

    floatx4 acc[4][4];
    #pragma unroll
    for (int i = 0; i < 4; ++i)
        #pragma unroll
        for (int j = 0; j < 4; ++j)
            acc[i][j] = (floatx4){0.f, 0.f, 0.f, 0.f};

    float4 ra[4], rb[4];
    const float4 fz = {0.f, 0.f, 0.f, 0.f};

    #pragma unroll
    for (int p = 0; p < 4; ++p) {
        int r = p * 32 + srow;
        long gr = row0 + r;
        ra[p] = (gr < M) ? *(const float4*)(A + gr * lda + sk) : fz;
        long gc = col0 + r;
        rb[p] = (gc < Ntot) ? *(const float4*)(BT + gc * ldbt + sk) : fz;
    }

    for (int k0 = 0; k0 < K; k0 += GBK) {
        #pragma unroll
        for (int p = 0; p < 4; ++p) {
            int off = (p * 32 + srow) * BKP + sk;
            short h0, h1, h2, h3, l0, l1, l2, l3;
            cvt_pair(ra[p].x, h0, l0); cvt_pair(ra[p].y, h1, l1);
            cvt_pair(ra[p].z, h2, l2); cvt_pair(ra[p].w, h3, l3);
            *(shortx4*)&AsH[off] = (shortx4){h0, h1, h2, h3};
            *(shortx4*)&AsL[off] = (shortx4){l0, l1, l2, l3};
            cvt_pair(rb[p].x, h0, l0); cvt_pair(rb[p].y, h1, l1);
            cvt_pair(rb[p].z, h2, l2); cvt_pair(rb[p].w, h3, l3);
            *(shortx4*)&BsH[off] = (shortx4){h0, h1, h2, h3};
            *(shortx4*)&BsL[off] = (shortx4){l0, l1, l2, l3};
        }
        __syncthreads();

        if (k0 + GBK < K) {
            int kn = k0 + GBK + sk;
            #pragma unroll
            for (int p = 0; p < 4; ++p) {
                int r = p * 32 + srow;
                long gr = row0 + r;
                ra[p] = (gr < M) ? *(const float4*)(A + gr * lda + kn) : fz;
                long gc = col0 + r;
                rb[p] = (gc < Ntot) ? *(const float4*)(BT + gc * ldbt + kn) : fz;
            }
        }

        bf16x8 aH[4], aL[4], bH[4], bL[4];
        #pragma unroll
        for (int i = 0; i < 4; ++i) {
            int off = (wm * 64 + i * 16 + l15) * BKP + quad * 8;
            aH[i] = *(const bf16x8*)&AsH[off];
            aL[i] = *(const bf16x8*)&AsL[off];
        }
        #pragma unroll
        for (int j = 0; j < 4; ++j) {
            int off = (wn * 64 + j * 16 + l15) * BKP + quad * 8;
            bH[j] = *(const bf16x8*)&BsH[off];
            bL[j] = *(const bf16x8*)&BsL[off];
        }
        #pragma unroll
        for (int i = 0; i < 4; ++i)
            #pragma unroll
            for (int j = 0; j < 4; ++j) {
                acc[i][j] = __builtin_amdgcn_mfma_f32_16x16x32_bf16(aH[i], bH[j], acc[i][j], 0, 0, 0);
                acc[i][j] = __builtin_amdgcn_mfma_f32_16x16x32_bf16(aH[i], bL[j], acc[i][j], 0, 0, 0);
                acc[i][j] = __builtin_amdgcn_mfma_f32_16x16x32_bf16(aL[i], bH[j], acc[i][j], 0, 0, 0);
            }
        __syncthreads();
    }

    float gate = 0.f;
    if (epilogue == 2) gate = 1.f / (1.f + expf(-skipGate[0]));

    #pragma unroll
    for (int i = 0; i < 4; ++i) {
        #pragma unroll
        for (int rr = 0; rr < 4; ++rr) {
            long grow = row0 + wm * 64 + i * 16 + quad * 4 + rr;
            if (grow >= M) continue;
            #pragma unroll
            for (int j = 0; j < 4; ++j) {
                long gcol = col0 + wn * 64 + j * 16 + l15;
                if (gcol >= Ntot) continue;
                float v = acc[i][j][rr];
                if (bias) v += bias[gcol];
                if (epilogue == 2) v = gate * v + (1.f - gate) * Xprev[grow * ldc + gcol];
                if (epilogue >= 1) v = fmaxf(v, 0.f);
                C[grow * ldc + gcol] = v;
            }
        }
    }
}

// ============ build fused transposed weight WbigT[640, F] + bias640 ============
__global__ void build_wbigT(
    const float* __restrict__ Wq, const float* __restrict__ bq,
    const float* __restrict__ Wk, const float* __restrict__ bk,
    const float* __restrict__ Wv, const float* __restrict__ bv,
    const float* __restrict__ arel, const float* __restrict__ mrel,
    float* __restrict__ WT, float* __restrict__ bias, int F)
{
    int idx = blockIdx.x * 256 + threadIdx.x;
    if (idx >= F * 640) return;
    int c = idx / F;
    int f = idx - c * F;
    float w, b = 0.f;
    if (c < 128) {
        w = Wq[(long)f * 128 + c];
        b = bq[c];
    } else {
        int cc = c - 128;
        const float* Wsrc; const float* bsrc; const float* T;
        if (cc < 256) { Wsrc = Wk; bsrc = bk; T = arel; }
        else { cc -= 256; Wsrc = Wv; bsrc = bv; T = mrel; }
        int r = cc >> 7, j = cc & 127, h = j >> 6, e = j & 63;
        const float* Trow = T + ((long)(r * 2 + h) * 4096 + e);
        const float* Wrow = Wsrc + (long)f * 128 + h * 64;
        float s = 0.f;
        for (int d = 0; d < 64; ++d) s += Wrow[d] * Trow[(long)d * 64];
        w = s;
        if (f == 0) {
            float sb = 0.f;
            const float* brow = bsrc + h * 64;
            for (int d = 0; d < 64; ++d) sb += brow[d] * Trow[(long)d * 64];
            b = sb;
        }
    }
    WT[idx] = w;
    if (f == 0) bias[c] = b;
}

__global__ void transpose128(const float* __restrict__ W, float* __restrict__ WT)
{
    int idx = blockIdx.x * 256 + threadIdx.x;   // 16384
    int c = idx >> 7, f = idx & 127;
    WT[idx] = W[f * 128 + c];
}

// ============ CSR build (edges fixed across layers: built once) ============
__global__ void csr_count_kernel(const int* __restrict__ dst, int* __restrict__ counts, int E)
{
    int e = blockIdx.x * 256 + threadIdx.x;
    if (e < E) atomicAdd(&counts[dst[e]], 1);
}

__global__ __launch_bounds__(1024) void csr_scan_kernel(
    const int* __restrict__ counts, int* __restrict__ offsets,
    int* __restrict__ cursor, int N, int E)
{
    __shared__ int part[1024];
    int t = threadIdx.x;
    int chunk = (N + 1023) / 1024;
    int a = t * chunk, b = a + chunk; if (b > N) b = N;
    int s = 0;
    for (int i = a; i < b; ++i) s += counts[i];
    part[t] = s;
    __syncthreads();
    for (int off = 1; off < 1024; off <<= 1) {
        int v = (t >= off) ? part[t - off] : 0;
        __syncthreads();
        if (t >= off) part[t] += v;
        __syncthreads();
    }
    int p = (t == 0) ? 0 : part[t - 1];
    for (int i = a; i < b; ++i) {
        offsets[i] = p; cursor[i] = p; p += counts[i];
    }
    if (t == 1023) offsets[N] = E;
}

__global__ void csr_fill_kernel(const int* __restrict__ src, const int* __restrict__ dst,
                                int* __restrict__ cursor, int* __restrict__ ssrc, int E)
{
    int e = blockIdx.x * 256 + threadIdx.x;
    if (e >= E) return;
    int pos = atomicAdd(&cursor[dst[e]], 1);
    ssrc[pos] = src[e];
}

// ============ node attention: one wave per (node, head), CSR walk, no atomics ====
__global__ __launch_bounds__(256) void node_attn_kernel(
    const float* __restrict__ qkv,
    const int* __restrict__ off0, const int* __restrict__ ss0,
    const int* __restrict__ off1, const int* __restrict__ ss1,
    const float* __restrict__ prel,     // [2][2] (r,h)
    float* __restrict__ out, int N)
{
    int wid = blockIdx.x * 4 + (threadIdx.x >> 6);
    int lane = threadIdx.x & 63;
    int d = wid >> 1;
    int h = wid & 1;
    if (d >= N) return;

    float q = qkv[(long)d * 640 + h * 64 + lane];
    float acc = 0.f;

    #pragma unroll
    for (int r = 0; r < 2; ++r) {
        const int* off = r ? off1 : off0;
        const int* ss  = r ? ss1  : ss0;
        const float* kr = qkv + 128 + r * 128 + h * 64 + lane;
        const float* vr = qkv + 384 + r * 128 + h * 64 + lane;
        float pr = prel[r * 2 + h] * 0.125f;   // includes 1/sqrt(64)
        int a = off[d], b = off[d + 1];
        float num = 0.f, den = 0.f;

        // software pipeline: prefetch edge i+1's k/v ahead of edge i's reduce
        float k = 0.f, v = 0.f;
        if (a < b) {
            long s = (long)ss[a] * 640;
            k = kr[s]; v = vr[s];
        }
        for (int i = a; i < b; ++i) {
            float kc = k, vc = v;
            if (i + 1 < b) {
                long s = (long)ss[i + 1] * 640;
                k = kr[s]; v = vr[s];
            }
            float p = q * kc;
            #pragma unroll
            for (int o = 32; o; o >>= 1) p += __shfl_xor(p, o, 64);
            float w = expf(p * pr);
            den += w;
            num = fmaf(w, vc, num);
        }
        acc += num / (den + 1e-16f);
    }

    out[(long)d * 128 + h * 64 + lane] =
        0.5f * acc * (1.f + erff(acc * 0.70710678118654752f));
}

// ============ f32 vector GEMM kept for tiny MLP ============
#define BM 64
#define BN 64
#define BK 16
__global__ __launch_bounds__(256) void gemm_bias_kernel(
    const float* __restrict__ A, int lda,
    const float* __restrict__ B, int ldb,
    const float* __restrict__ bias,
    float* __restrict__ C, int ldc,
    int M, int K, int epilogue)
{
    __shared__ float As[BK][BM + 4];
    __shared__ float Bs[BK][BN + 4];
    const int t = threadIdx.x;
    const int row0 = blockIdx.y * BM;
    const int col0 = blockIdx.x * BN;
    const int tm = (t >> 4) << 2;
    const int tn = (t & 15) << 2;
    float acc[4][4] = {};
    for (int k0 = 0; k0 < K; k0 += BK) {
        #pragma unroll
        for (int i = 0; i < 4; ++i) {
            int idx = t + i * 256;
            int m = idx >> 4, kk = idx & 15;
            int gm = row0 + m;
            As[kk][m] = (gm < M) ? A[(long)gm * lda + (k0 + kk)] : 0.f;
        }
        #pragma unroll
        for (int i = 0; i < 4; ++i) {
            int idx = t + i * 256;
            int kk = idx >> 6, n = idx & 63;
            Bs[kk][n] = B[(long)(k0 + kk) * ldb + (col0 + n)];
        }
        __syncthreads();
        #pragma unroll
        for (int kk = 0; kk < BK; ++kk) {
            float a[4], b[4];
            #pragma unroll
            for (int i = 0; i < 4; ++i) a[i] = As[kk][tm + i];
            #pragma unroll
            for (int j = 0; j < 4; ++j) b[j] = Bs[kk][tn + j];
            #pragma unroll
            for (int i = 0; i < 4; ++i)
                #pragma unroll
                for (int j = 0; j < 4; ++j)
                    acc[i][j] = fmaf(a[i], b[j], acc[i][j]);
        }
        __syncthreads();
    }
    #pragma unroll
    for (int i = 0; i < 4; ++i) {
        int gm = row0 + tm + i;
        if (gm >= M) continue;
        #pragma unroll
        for (int j = 0; j < 4; ++j) {
            int gn = col0 + tn + j;
            float v = acc[i][j];
            if (bias) v += bias[gn];
            if (epilogue >= 1) v = fmaxf(v, 0.f);
            C[(long)gm * ldc + gn] = v;
        }
    }
}

// ============ pooling ============
__device__ inline int lower_bound_i(const int* __restrict__ a, int n, int v)
{
    int lo = 0, hi = n;
    while (lo < hi) { int mid = (lo + hi) >> 1; if (a[mid] < v) lo = mid + 1; else hi = mid; }
    return lo;
}

__global__ void pool_kernel(const float* __restrict__ h, const int* __restrict__ batch,
                            float* __restrict__ s, int N)
{
    int g = blockIdx.x, part = blockIdx.y, c = threadIdx.x;
    int start = lower_bound_i(batch, N, g);
    int end = lower_bound_i(batch, N, g + 1);
    int cnt = end - start, parts = gridDim.y;
    int chunk = (cnt + parts - 1) / parts;
    int a = start + part * chunk;
    int b = a + chunk; if (b > end) b = end;
    if (a >= b) return;
    float sum = 0.f;
    for (int n = a; n < b; ++n) sum += h[(long)n * HDIM + c];
    atomicAdd(&s[g * HDIM + c], sum);
}

__global__ void pool_finalize(const float* __restrict__ s, const int* __restrict__ batch,
                              float* __restrict__ g_out, int N)
{
    int g = blockIdx.x, c = threadIdx.x;
    int start = lower_bound_i(batch, N, g);
    int end = lower_bound_i(batch, N, g + 1);
    float cnt = (float)((end - start) > 1 ? (end - start) : 1);
    g_out[g * HDIM + c] = s[g * HDIM + c] / cnt;
}

// ============ host ============
extern "C" void kernel_launch(void* const* d_in, const int* in_sizes, int n_in,
                              void* d_out, int out_size, void* d_ws, size_t ws_size,
                              hipStream_t stream)
{
    const float* x      = (const float*)d_in[0];
    const int*   e0     = (const int*)d_in[1];
    const int*   e1     = (const int*)d_in[2];
    const int*   batch  = (const int*)d_in[3];
    const float* W_k1   = (const float*)d_in[4];
    const float* W_q1   = (const float*)d_in[5];
    const float* W_v1   = (const float*)d_in[6];
    const float* a_rel1 = (const float*)d_in[7];
    const float* m_rel1 = (const float*)d_in[8];
    const float* W_a1   = (const float*)d_in[9];
    const float* W_k23  = (const float*)d_in[10];
    const float* W_q23  = (const float*)d_in[11];
    const float* W_v23  = (const float*)d_in[12];
    const float* a_rel23= (const float*)d_in[13];
    const float* m_rel23= (const float*)d_in[14];
    const float* W_a23  = (const float*)d_in[15];
    const float* W_m1   = (const float*)d_in[16];
    const float* W_m2   = (const float*)d_in[17];
    const float* b_k1   = (const float*)d_in[18];
    const float* b_q1   = (const float*)d_in[19];
    const float* b_v1   = (const float*)d_in[20];
    const float* b_a1   = (const float*)d_in[21];
    const float* b_k23  = (const float*)d_in[22];
    const float* b_q23  = (const float*)d_in[23];
    const float* b_v23  = (const float*)d_in[24];
    const float* b_a23  = (const float*)d_in[25];
    const float* skip23 = (const float*)d_in[26];
    const float* b_m1   = (const float*)d_in[27];
    const float* b_m2   = (const float*)d_in[28];
    const float* p_rel1 = (const float*)d_in[29];
    const float* p_rel23= (const float*)d_in[30];

    const int N = N_NODES_C;
    const int E = in_sizes[1] / 2;
    const int F = in_sizes[0] / N;            // 512
    const long NN = (long)N * HDIM;           // 6.4M

    // ---- workspace layout (no aliasing) ----
    float* ws   = (float*)d_ws;
    float* QKV  = ws;                          // N*640
    float* ACC  = QKV + (long)N * 640;         // NN (gelu(attention) output)
    float* H1   = ACC + NN;                    // NN
    float* H2   = H1 + NN;                     // NN
    float* WT   = H2 + NN;                     // 640*512 max
    float* B640 = WT + 640 * 512;              // 640
    float* S    = B640 + 640;                  // 64*128
    float* GM   = S + N_GRAPHS_C * HDIM;
    float* M1   = GM + N_GRAPHS_C * HDIM;
    int*   ip   = (int*)(M1 + N_GRAPHS_C * HDIM);
    int*   off0 = ip;                          // N+1
    int*   ss0  = off0 + (N + 1);              // E
    int*   off1 = ss0 + E;                     // N+1
    int*   ss1  = off1 + (N + 1);              // E
    int*   counts = ss1 + E;                   // N
    int*   cursor = counts + N;                // N
    size_t needed = (size_t)((char*)(cursor + N) - (char*)d_ws);
    if (ws_size < needed) return;

    // ---- build CSR for both relations (once; edges fixed across layers) ----
    {
        int eb = (E + 255) / 256;
        hipMemsetAsync(counts, 0, (size_t)N * sizeof(int), stream);
        csr_count_kernel<<<eb, 256, 0, stream>>>(e0 + E, counts, E);
        csr_scan_kernel<<<1, 1024, 0, stream>>>(counts, off0, cursor, N, E);
        csr_fill_kernel<<<eb, 256, 0, stream>>>(e0, e0 + E, cursor, ss0, E);

        hipMemsetAsync(counts, 0, (size_t)N * sizeof(int), stream);
        csr_count_kernel<<<eb, 256, 0, stream>>>(e1 + E, counts, E);
        csr_scan_kernel<<<1, 1024, 0, stream>>>(counts, off1, cursor, N, E);
        csr_fill_kernel<<<eb, 256, 0, stream>>>(e1, e1 + E, cursor, ss1, E);
    }

    auto mfma_gemm = [&](const float* A, int lda, const float* BTp, int ldbt,
                         const float* bias, float* Cp, int ldc, int M, int Nc, int K,
                         int epi, const float* gate, const float* xprev) {
        dim3 grid(Nc / GBN, (M + GBM - 1) / GBM);
        gemm_mfma_split<<<grid, 256, 0, stream>>>(A, lda, BTp, ldbt, bias, Cp, ldc,
                                                  M, Nc, K, epi, gate, xprev);
    };

    auto run_layer = [&](const float* hin, int Fin,
                         const float* Wk, const float* bk,
                         const float* Wq, const float* bq,
                         const float* Wv, const float* bv,
                         const float* arel, const float* mrel, const float* prel,
                         const float* Wa, const float* ba,
                         const float* gate, float* hout) {
        int tot = Fin * 640;
        build_wbigT<<<(tot + 255) / 256, 256, 0, stream>>>(Wq, bq, Wk, bk, Wv, bv,
                                                           arel, mrel, WT, B640, Fin);
        mfma_gemm(hin, Fin, WT, Fin, B640, QKV, 640, N, 640, Fin, 0, nullptr, nullptr);

        // fused attention + softmax + relation-sum + gelu, no atomics
        int waves = N * 2;
        node_attn_kernel<<<(waves + 3) / 4, 256, 0, stream>>>(
            QKV, off0, ss0, off1, ss1, prel, ACC, N);

        transpose128<<<64, 256, 0, stream>>>(Wa, WT);
        mfma_gemm(ACC, 128, WT, 128, ba, hout, 128, N, 128, 128,
                  gate ? 2 : 1, gate, hin);
    };

    run_layer(x, F, W_k1, b_k1, W_q1, b_q1, W_v1, b_v1,
              a_rel1, m_rel1, p_rel1, W_a1, b_a1, nullptr, H1);
    run_layer(H1, HDIM, W_k23, b_k23, W_q23, b_q23, W_v23, b_v23,
              a_rel23, m_rel23, p_rel23, W_a23, b_a23, skip23, H2);
    run_layer(H2, HDIM, W_k23 + 16384, b_k23 + 128, W_q23 + 16384, b_q23 + 128,
              W_v23 + 16384, b_v23 + 128, a_rel23 + 16384, m_rel23 + 16384,
              p_rel23 + 4, W_a23 + 16384, b_a23 + 128, skip23 + 1, H1);

    hipMemsetAsync(S, 0, (size_t)N_GRAPHS_C * HDIM * sizeof(float), stream);
    dim3 pg(N_GRAPHS_C, 8);
    pool_kernel<<<pg, HDIM, 0, stream>>>(H1, batch, S, N);
    pool_finalize<<<N_GRAPHS_C, HDIM, 0, stream>>>(S, batch, GM, N);

    {
        dim3 g1(128 / BN, 1);
        gemm_bias_kernel<<<g1, 256, 0, stream>>>(GM, 128, W_m1, 128, b_m1, M1, 128,
                                                 N_GRAPHS_C, 128, 1);
        dim3 g2(256 / BN, 1);
        gemm_bias_kernel<<<g2, 256, 0, stream>>>(M1, 128, W_m2, 256, b_m2,
                                                 (float*)d_out, 256, N_GRAPHS_C, 128, 0);
    }
}

// Round 7
// 1122.106 us; speedup vs baseline: 2.6523x; 1.0944x over previous
//
#include <hip/hip_runtime.h>
#include <math.h>

#define N_NODES_C 50000
#define N_GRAPHS_C 64
#define HDIM 128

typedef short bf16x8 __attribute__((ext_vector_type(8)));
typedef short shortx4 __attribute__((ext_vector_type(4)));
typedef float floatx4 __attribute__((ext_vector_type(4)));

// split f32 -> hi (truncated bf16) + lo (bf16 of exact residual)
__device__ __forceinline__ void cvt_pair(float x, short& h, short& l) {
    union { float f; unsigned u; } a; a.f = x;
    h = (short)(a.u >> 16);
    union { unsigned u; float f; } b; b.u = a.u & 0xFFFF0000u;
    union { float f; unsigned u; } c; c.f = x - b.f;   // exact residual
    l = (short)(c.u >> 16);
}

__device__ __forceinline__ float b2f(short s) {
    union { unsigned u; float f; } x; x.u = ((unsigned)(unsigned short)s) << 16;
    return x.f;
}

// async global->LDS copy, 16 B per lane, LDS dest = wave-uniform base + lane*16
__device__ __forceinline__ void gld_lds16(const void* gsrc, void* ldst) {
    __builtin_amdgcn_global_load_lds(
        (const __attribute__((address_space(1))) unsigned int*)gsrc,
        (__attribute__((address_space(3))) unsigned int*)ldst,
        16, 0, 0);
}

// ============ MFMA GEMM with global_load_lds staging ============
// C[M,N] = A[M,K] @ BT[N,K]^T (+bias). A: f32 (AF32=1) or bf16 hi/lo planes.
// B: always bf16 hi/lo planes. Split-bf16 3-MFMA for f32-class accuracy.
// mode 0: Cf32 = v + bias          (ldc = Ntot)
// mode 2: planes = relu(v + bias)  (ldc = 128)
// mode 3: planes = relu(gate*v+bias' + (1-gate)*prev)  (ldc = 128)
#define GBM 128
#define GBN 128
#define GBK 32

template<int AF32>
__global__ __launch_bounds__(256, 2) void gemm_planes(
    const void* __restrict__ Aptr, const short* __restrict__ Alo, int lda,
    const short* __restrict__ Bhi, const short* __restrict__ Blo, int ldbt,
    const float* __restrict__ bias,
    float* __restrict__ Cf, short* __restrict__ Chi, short* __restrict__ Clo,
    int M, int Ntot, int K,
    int mode, const float* __restrict__ skipGate,
    const short* __restrict__ Phi, const short* __restrict__ Plo)
{
    __shared__ __align__(16) short AsH[AF32 ? (GBM * GBK * 2) : (GBM * GBK)];
    __shared__ __align__(16) short AsL[AF32 ? 8 : (GBM * GBK)];
    __shared__ __align__(16) short BsH[GBN * GBK];
    __shared__ __align__(16) short BsL[GBN * GBK];

    const int t = threadIdx.x;
    const int lane = t & 63;
    const int wave = t >> 6;
    const int wm = wave & 1, wn = wave >> 1;
    const int quad = lane >> 4, l15 = lane & 15;
    const long row0 = (long)blockIdx.y * GBM;
    const long col0 = (long)blockIdx.x * GBN;

    floatx4 acc[4][4];
    #pragma unroll
    for (int i = 0; i < 4; ++i)
        #pragma unroll
        for (int j = 0; j < 4; ++j)
            acc[i][j] = (floatx4){0.f, 0.f, 0.f, 0.f};

    for (int k0 = 0; k0 < K; k0 += GBK) {
        if (AF32) {
            // f32 tile 128x32 = 16 KB, 16 chunks of 1 KB (8 rows each).
            // XOR-swizzle granules so fragment ds_reads are ~conflict-free.
            const float* Af = (const float*)Aptr;
            int r8 = lane >> 3, kc8 = lane & 7;
            #pragma unroll
            for (int cc = 0; cc < 4; ++cc) {
                int ch = wave * 4 + cc;
                long gr = row0 + ch * 8 + r8;
                if (gr > M - 1) gr = M - 1;
                gld_lds16(Af + gr * lda + k0 + ((kc8 ^ r8) << 2),
                          (short*)AsH + ch * 512);
            }
        } else {
            const short* Ahi = (const short*)Aptr;
            int r16 = lane >> 2, g4 = lane & 3;
            #pragma unroll
            for (int cc = 0; cc < 2; ++cc) {
                int ch = wave * 2 + cc;
                long gr = row0 + ch * 16 + r16;
                if (gr > M - 1) gr = M - 1;
                long go = gr * lda + k0 + g4 * 8;
                gld_lds16(Ahi + go, AsH + ch * 512);
                gld_lds16(Alo + go, AsL + ch * 512);
            }
        }
        {
            int r16 = lane >> 2, g4 = lane & 3;
            #pragma unroll
            for (int cc = 0; cc < 2; ++cc) {
                int ch = wave * 2 + cc;
                long gc = col0 + ch * 16 + r16;
                if (gc > Ntot - 1) gc = Ntot - 1;
                long go = gc * ldbt + k0 + g4 * 8;
                gld_lds16(Bhi + go, BsH + ch * 512);
                gld_lds16(Blo + go, BsL + ch * 512);
            }
        }
        __syncthreads();   // compiler inserts vmcnt wait for global_load_lds

        bf16x8 aH[4], aL[4], bH[4], bL[4];
        if (AF32) {
            #pragma unroll
            for (int i = 0; i < 4; ++i) {
                int row = wm * 64 + i * 16 + l15;
                const float* fr = (const float*)AsH + row * 32;
                int x7 = row & 7;
                float4 f0 = *(const float4*)(fr + (((quad * 2)     ^ x7) << 2));
                float4 f1 = *(const float4*)(fr + (((quad * 2 + 1) ^ x7) << 2));
                short h0,h1,h2,h3,h4,h5,h6,h7, l0,l1,l2,l3,l4,l5,l6,l7;
                cvt_pair(f0.x,h0,l0); cvt_pair(f0.y,h1,l1);
                cvt_pair(f0.z,h2,l2); cvt_pair(f0.w,h3,l3);
                cvt_pair(f1.x,h4,l4); cvt_pair(f1.y,h5,l5);
                cvt_pair(f1.z,h6,l6); cvt_pair(f1.w,h7,l7);
                aH[i] = (bf16x8){h0,h1,h2,h3,h4,h5,h6,h7};
                aL[i] = (bf16x8){l0,l1,l2,l3,l4,l5,l6,l7};
            }
        } else {
            #pragma unroll
            for (int i = 0; i < 4; ++i) {
                int off = (wm * 64 + i * 16 + l15) * 32 + quad * 8;
                aH[i] = *(const bf16x8*)&AsH[off];
                aL[i] = *(const bf16x8*)&AsL[off];
            }
        }
        #pragma unroll
        for (int j = 0; j < 4; ++j) {
            int off = (wn * 64 + j * 16 + l15) * 32 + quad * 8;
            bH[j] = *(const bf16x8*)&BsH[off];
            bL[j] = *(const bf16x8*)&BsL[off];
        }
        #pragma unroll
        for (int i = 0; i < 4; ++i)
            #pragma unroll
            for (int j = 0; j < 4; ++j) {
                acc[i][j] = __builtin_amdgcn_mfma_f32_16x16x32_bf16(aH[i], bH[j], acc[i][j], 0, 0, 0);
                acc[i][j] = __builtin_amdgcn_mfma_f32_16x16x32_bf16(aH[i], bL[j], acc[i][j], 0, 0, 0);
                acc[i][j] = __builtin_amdgcn_mfma_f32_16x16x32_bf16(aL[i], bH[j], acc[i][j], 0, 0, 0);
            }
        __syncthreads();
    }

    float gate = 0.f;
    if (mode == 3) gate = 1.f / (1.f + expf(-skipGate[0]));

    #pragma unroll
    for (int i = 0; i < 4; ++i) {
        #pragma unroll
        for (int rr = 0; rr < 4; ++rr) {
            long grow = row0 + wm * 64 + i * 16 + quad * 4 + rr;
            if (grow >= M) continue;
            #pragma unroll
            for (int j = 0; j < 4; ++j) {
                long gcol = col0 + wn * 64 + j * 16 + l15;
                if (gcol >= Ntot) continue;
                float v = acc[i][j][rr];
                if (bias) v += bias[gcol];
                if (mode == 0) {
                    Cf[grow * Ntot + gcol] = v;
                } else {
                    if (mode == 3) {
                        long po = grow * 128 + gcol;
                        float pv = b2f(Phi[po]) + b2f(Plo[po]);
                        v = gate * v + (1.f - gate) * pv;
                    }
                    v = fmaxf(v, 0.f);
                    short hh, ll; cvt_pair(v, hh, ll);
                    Chi[grow * 128 + gcol] = hh;
                    Clo[grow * 128 + gcol] = ll;
                }
            }
        }
    }
}

// ============ build fused WbigT[640, F] as bf16 hi/lo planes + bias640 ============
// cols: [0,128) q | [128,384) k_r | [384,640) v_r ; one c per blockIdx.y
__global__ __launch_bounds__(256) void build_wbigT_p(
    const float* __restrict__ Wq, const float* __restrict__ bq,
    const float* __restrict__ Wk, const float* __restrict__ bk,
    const float* __restrict__ Wv, const float* __restrict__ bv,
    const float* __restrict__ arel, const float* __restrict__ mrel,
    short* __restrict__ WThi, short* __restrict__ WTlo,
    float* __restrict__ bias, int F)
{
    __shared__ float Trow[64];
    int c = blockIdx.y;
    int f = blockIdx.x * 256 + threadIdx.x;
    float w = 0.f, b = 0.f;
    if (c < 128) {
        if (f < F) w = Wq[(long)f * 128 + c];
        b = bq[c];
    } else {
        int cc = c - 128;
        const float* Wsrc; const float* bsrc; const float* T;
        if (cc < 256) { Wsrc = Wk; bsrc = bk; T = arel; }
        else { cc -= 256; Wsrc = Wv; bsrc = bv; T = mrel; }
        int r = cc >> 7, j = cc & 127, h = j >> 6, e = j & 63;
        const float* Tr = T + (long)(r * 2 + h) * 4096 + e;
        if (threadIdx.x < 64) Trow[threadIdx.x] = Tr[(long)threadIdx.x * 64];
        __syncthreads();
        if (f < F) {
            const float* Wrow = Wsrc + (long)f * 128 + h * 64;
            float s = 0.f;
            #pragma unroll 4
            for (int d = 0; d < 64; ++d) s = fmaf(Wrow[d], Trow[d], s);
            w = s;
        }
        if (f == 0) {
            const float* brow = bsrc + h * 64;
            float sb = 0.f;
            for (int d = 0; d < 64; ++d) sb = fmaf(brow[d], Trow[d], sb);
            b = sb;
        }
    }
    if (f < F) {
        short hh, ll; cvt_pair(w, hh, ll);
        WThi[(long)c * F + f] = hh;
        WTlo[(long)c * F + f] = ll;
    }
    if (f == 0) bias[c] = b;
}

// W[128,128] -> WT planes [128,128] bf16 hi/lo
__global__ void transpose128p(const float* __restrict__ W,
                              short* __restrict__ hi, short* __restrict__ lo)
{
    int idx = blockIdx.x * 256 + threadIdx.x;   // 16384
    int c = idx >> 7, f = idx & 127;
    short hh, ll; cvt_pair(W[f * 128 + c], hh, ll);
    hi[idx] = hh; lo[idx] = ll;
}

// ============ CSR build (edges fixed across layers: built once) ============
__global__ void csr_count_kernel(const int* __restrict__ dst, int* __restrict__ counts, int E)
{
    int e = blockIdx.x * 256 + threadIdx.x;
    if (e < E) atomicAdd(&counts[dst[e]], 1);
}

__global__ __launch_bounds__(1024) void csr_scan_kernel(
    const int* __restrict__ counts, int* __restrict__ offsets,
    int* __restrict__ cursor, int N, int E)
{
    __shared__ int part[1024];
    int t = threadIdx.x;
    int chunk = (N + 1023) / 1024;
    int a = t * chunk, b = a + chunk; if (b > N) b = N;
    int s = 0;
    for (int i = a; i < b; ++i) s += counts[i];
    part[t] = s;
    __syncthreads();
    for (int off = 1; off < 1024; off <<= 1) {
        int v = (t >= off) ? part[t - off] : 0;
        __syncthreads();
        if (t >= off) part[t] += v;
        __syncthreads();
    }
    int p = (t == 0) ? 0 : part[t - 1];
    for (int i = a; i < b; ++i) {
        offsets[i] = p; cursor[i] = p; p += counts[i];
    }
    if (t == 1023) offsets[N] = E;
}

__global__ void csr_fill_kernel(const int* __restrict__ src, const int* __restrict__ dst,
                                int* __restrict__ cursor, int* __restrict__ ssrc, int E)
{
    int e = blockIdx.x * 256 + threadIdx.x;
    if (e >= E) return;
    int pos = atomicAdd(&cursor[dst[e]], 1);
    ssrc[pos] = src[e];
}

// ============ node attention: one wave per (node, head), 4 edges/chunk ============
// 16 lanes per edge, float4 gathers, no atomics. Writes ACC hi/lo planes.
__global__ __launch_bounds__(256) void node_attn_kernel(
    const float* __restrict__ qkv,
    const int* __restrict__ off0, const int* __restrict__ ss0,
    const int* __restrict__ off1, const int* __restrict__ ss1,
    const float* __restrict__ prel,     // [2][2] (r,h)
    short* __restrict__ ohi, short* __restrict__ olo, int N)
{
    int wid = blockIdx.x * 4 + (threadIdx.x >> 6);
    int lane = threadIdx.x & 63;
    int d = wid >> 1, h = wid & 1;
    if (d >= N) return;
    int g = lane >> 4, l = lane & 15;

    float4 q4 = *(const float4*)(qkv + (long)d * 640 + h * 64 + l * 4);
    int a0 = off0[d], b0 = off0[d + 1];
    int a1 = off1[d], b1 = off1[d + 1];

    float4 accv = {0.f, 0.f, 0.f, 0.f};

    #pragma unroll
    for (int r = 0; r < 2; ++r) {
        const int* ss = r ? ss1 : ss0;
        int a = r ? a1 : a0, b = r ? b1 : b0;
        const float* kp = qkv + 128 + r * 128 + h * 64 + l * 4;
        const float* vp = qkv + 384 + r * 128 + h * 64 + l * 4;
        float pr = prel[r * 2 + h] * 0.125f;   // includes 1/sqrt(64)

        float4 num = {0.f, 0.f, 0.f, 0.f};
        float den = 0.f;
        for (int c = a; c < b; c += 4) {
            int e = c + g;
            int sidx = ss[(e < b) ? e : (b - 1)];
            long so = (long)sidx * 640;
            float4 k4 = *(const float4*)(kp + so);
            float4 v4 = *(const float4*)(vp + so);
            float p = q4.x * k4.x + q4.y * k4.y + q4.z * k4.z + q4.w * k4.w;
            p += __shfl_xor(p, 1, 16);
            p += __shfl_xor(p, 2, 16);
            p += __shfl_xor(p, 4, 16);
            p += __shfl_xor(p, 8, 16);
            float w = (e < b) ? expf(p * pr) : 0.f;
            den += w;
            num.x = fmaf(w, v4.x, num.x);
            num.y = fmaf(w, v4.y, num.y);
            num.z = fmaf(w, v4.z, num.z);
            num.w = fmaf(w, v4.w, num.w);
        }
        // combine the 4 edge groups
        num.x += __shfl_xor(num.x, 16, 64); num.x += __shfl_xor(num.x, 32, 64);
        num.y += __shfl_xor(num.y, 16, 64); num.y += __shfl_xor(num.y, 32, 64);
        num.z += __shfl_xor(num.z, 16, 64); num.z += __shfl_xor(num.z, 32, 64);
        num.w += __shfl_xor(num.w, 16, 64); num.w += __shfl_xor(num.w, 32, 64);
        den   += __shfl_xor(den,   16, 64); den   += __shfl_xor(den,   32, 64);
        float inv = 1.f / (den + 1e-16f);
        accv.x = fmaf(num.x, inv, accv.x);
        accv.y = fmaf(num.y, inv, accv.y);
        accv.z = fmaf(num.z, inv, accv.z);
        accv.w = fmaf(num.w, inv, accv.w);
    }

    if (g == 0) {
        const float is2 = 0.70710678118654752f;
        float o0 = 0.5f * accv.x * (1.f + erff(accv.x * is2));
        float o1 = 0.5f * accv.y * (1.f + erff(accv.y * is2));
        float o2 = 0.5f * accv.z * (1.f + erff(accv.z * is2));
        float o3 = 0.5f * accv.w * (1.f + erff(accv.w * is2));
        short h0,h1,h2,h3, l0,l1,l2,l3;
        cvt_pair(o0,h0,l0); cvt_pair(o1,h1,l1);
        cvt_pair(o2,h2,l2); cvt_pair(o3,h3,l3);
        long oo = (long)d * 128 + h * 64 + l * 4;
        *(shortx4*)(ohi + oo) = (shortx4){h0,h1,h2,h3};
        *(shortx4*)(olo + oo) = (shortx4){l0,l1,l2,l3};
    }
}

// ============ f32 vector GEMM kept for tiny MLP ============
#define BM 64
#define BN 64
#define BK 16
__global__ __launch_bounds__(256) void gemm_bias_kernel(
    const float* __restrict__ A, int lda,
    const float* __restrict__ B, int ldb,
    const float* __restrict__ bias,
    float* __restrict__ C, int ldc,
    int M, int K, int epilogue)
{
    __shared__ float As[BK][BM + 4];
    __shared__ float Bs[BK][BN + 4];
    const int t = threadIdx.x;
    const int row0 = blockIdx.y * BM;
    const int col0 = blockIdx.x * BN;
    const int tm = (t >> 4) << 2;
    const int tn = (t & 15) << 2;
    float acc[4][4] = {};
    for (int k0 = 0; k0 < K; k0 += BK) {
        #pragma unroll
        for (int i = 0; i < 4; ++i) {
            int idx = t + i * 256;
            int m = idx >> 4, kk = idx & 15;
            int gm = row0 + m;
            As[kk][m] = (gm < M) ? A[(long)gm * lda + (k0 + kk)] : 0.f;
        }
        #pragma unroll
        for (int i = 0; i < 4; ++i) {
            int idx = t + i * 256;
            int kk = idx >> 6, n = idx & 63;
            Bs[kk][n] = B[(long)(k0 + kk) * ldb + (col0 + n)];
        }
        __syncthreads();
        #pragma unroll
        for (int kk = 0; kk < BK; ++kk) {
            float a[4], b[4];
            #pragma unroll
            for (int i = 0; i < 4; ++i) a[i] = As[kk][tm + i];
            #pragma unroll
            for (int j = 0; j < 4; ++j) b[j] = Bs[kk][tn + j];
            #pragma unroll
            for (int i = 0; i < 4; ++i)
                #pragma unroll
                for (int j = 0; j < 4; ++j)
                    acc[i][j] = fmaf(a[i], b[j], acc[i][j]);
        }
        __syncthreads();
    }
    #pragma unroll
    for (int i = 0; i < 4; ++i) {
        int gm = row0 + tm + i;
        if (gm >= M) continue;
        #pragma unroll
        for (int j = 0; j < 4; ++j) {
            int gn = col0 + tn + j;
            float v = acc[i][j];
            if (bias) v += bias[gn];
            if (epilogue >= 1) v = fmaxf(v, 0.f);
            C[(long)gm * ldc + gn] = v;
        }
    }
}

// ============ pooling (reads bf16 hi/lo planes) ============
__device__ inline int lower_bound_i(const int* __restrict__ a, int n, int v)
{
    int lo = 0, hi = n;
    while (lo < hi) { int mid = (lo + hi) >> 1; if (a[mid] < v) lo = mid + 1; else hi = mid; }
    return lo;
}

__global__ void pool_kernel(const short* __restrict__ hhi, const short* __restrict__ hlo,
                            const int* __restrict__ batch,
                            float* __restrict__ s, int N)
{
    int g = blockIdx.x, part = blockIdx.y, c = threadIdx.x;
    int start = lower_bound_i(batch, N, g);
    int end = lower_bound_i(batch, N, g + 1);
    int cnt = end - start, parts = gridDim.y;
    int chunk = (cnt + parts - 1) / parts;
    int a = start + part * chunk;
    int b = a + chunk; if (b > end) b = end;
    if (a >= b) return;
    float sum = 0.f;
    for (int n = a; n < b; ++n) {
        long o = (long)n * HDIM + c;
        sum += b2f(hhi[o]) + b2f(hlo[o]);
    }
    atomicAdd(&s[g * HDIM + c], sum);
}

__global__ void pool_finalize(const float* __restrict__ s, const int* __restrict__ batch,
                              float* __restrict__ g_out, int N)
{
    int g = blockIdx.x, c = threadIdx.x;
    int start = lower_bound_i(batch, N, g);
    int end = lower_bound_i(batch, N, g + 1);
    float cnt = (float)((end - start) > 1 ? (end - start) : 1);
    g_out[g * HDIM + c] = s[g * HDIM + c] / cnt;
}

// ============ host ============
extern "C" void kernel_launch(void* const* d_in, const int* in_sizes, int n_in,
                              void* d_out, int out_size, void* d_ws, size_t ws_size,
                              hipStream_t stream)
{
    const float* x      = (const float*)d_in[0];
    const int*   e0     = (const int*)d_in[1];
    const int*   e1     = (const int*)d_in[2];
    const int*   batch  = (const int*)d_in[3];
    const float* W_k1   = (const float*)d_in[4];
    const float* W_q1   = (const float*)d_in[5];
    const float* W_v1   = (const float*)d_in[6];
    const float* a_rel1 = (const float*)d_in[7];
    const float* m_rel1 = (const float*)d_in[8];
    const float* W_a1   = (const float*)d_in[9];
    const float* W_k23  = (const float*)d_in[10];
    const float* W_q23  = (const float*)d_in[11];
    const float* W_v23  = (const float*)d_in[12];
    const float* a_rel23= (const float*)d_in[13];
    const float* m_rel23= (const float*)d_in[14];
    const float* W_a23  = (const float*)d_in[15];
    const float* W_m1   = (const float*)d_in[16];
    const float* W_m2   = (const float*)d_in[17];
    const float* b_k1   = (const float*)d_in[18];
    const float* b_q1   = (const float*)d_in[19];
    const float* b_v1   = (const float*)d_in[20];
    const float* b_a1   = (const float*)d_in[21];
    const float* b_k23  = (const float*)d_in[22];
    const float* b_q23  = (const float*)d_in[23];
    const float* b_v23  = (const float*)d_in[24];
    const float* b_a23  = (const float*)d_in[25];
    const float* skip23 = (const float*)d_in[26];
    const float* b_m1   = (const float*)d_in[27];
    const float* b_m2   = (const float*)d_in[28];
    const float* p_rel1 = (const float*)d_in[29];
    const float* p_rel23= (const float*)d_in[30];

    const int N = N_NODES_C;
    const int E = in_sizes[1] / 2;
    const int F = in_sizes[0] / N;            // 512
    const long NP = (long)N * HDIM;           // 6.4M plane elements

    // ---- workspace layout ----
    float* ws    = (float*)d_ws;
    float* QKV   = ws;                                  // N*640 f32 (128 MB)
    short* ACChi = (short*)(QKV + (long)N * 640);       // 6 planes, 12.8 MB each
    short* ACClo = ACChi + NP;
    short* H1hi  = ACClo + NP;
    short* H1lo  = H1hi + NP;
    short* H2hi  = H1lo + NP;
    short* H2lo  = H2hi + NP;
    short* WThi  = H2lo + NP;                           // 640*512 max
    short* WTlo  = WThi + 640 * 512;
    short* WaThi = WTlo + 640 * 512;                    // 128*128
    short* WaTlo = WaThi + 128 * 128;
    float* B640  = (float*)(WaTlo + 128 * 128);         // 640
    float* S     = B640 + 640;
    float* GM    = S + N_GRAPHS_C * HDIM;
    float* M1    = GM + N_GRAPHS_C * HDIM;
    int*   off0  = (int*)(M1 + N_GRAPHS_C * HDIM);      // N+1
    int*   ss0   = off0 + (N + 1);                      // E
    int*   off1  = ss0 + E;                             // N+1
    int*   ss1   = off1 + (N + 1);                      // E
    int*   counts = (int*)QKV;                          // alias: dead before QKV written
    int*   cursor = counts + N;
    size_t needed = (size_t)((char*)(ss1 + E) - (char*)d_ws);
    if (ws_size < needed) return;

    // ---- build CSR once (edges fixed across layers) ----
    {
        int eb = (E + 255) / 256;
        hipMemsetAsync(counts, 0, (size_t)N * sizeof(int), stream);
        csr_count_kernel<<<eb, 256, 0, stream>>>(e0 + E, counts, E);
        csr_scan_kernel<<<1, 1024, 0, stream>>>(counts, off0, cursor, N, E);
        csr_fill_kernel<<<eb, 256, 0, stream>>>(e0, e0 + E, cursor, ss0, E);

        hipMemsetAsync(counts, 0, (size_t)N * sizeof(int), stream);
        csr_count_kernel<<<eb, 256, 0, stream>>>(e1 + E, counts, E);
        csr_scan_kernel<<<1, 1024, 0, stream>>>(counts, off1, cursor, N, E);
        csr_fill_kernel<<<eb, 256, 0, stream>>>(e1, e1 + E, cursor, ss1, E);
    }

    auto run_layer = [&](const void* Ain, const short* AinLo, int AF, int Fin,
                         const float* Wk, const float* bk,
                         const float* Wq, const float* bq,
                         const float* Wv, const float* bv,
                         const float* arel, const float* mrel, const float* prel,
                         const float* Wa, const float* ba,
                         const float* gate, const short* skipHi, const short* skipLo,
                         short* outHi, short* outLo) {
        dim3 bg((Fin + 255) / 256, 640);
        build_wbigT_p<<<bg, 256, 0, stream>>>(Wq, bq, Wk, bk, Wv, bv,
                                              arel, mrel, WThi, WTlo, B640, Fin);
        dim3 qg(640 / GBN, (N + GBM - 1) / GBM);
        if (AF)
            gemm_planes<1><<<qg, 256, 0, stream>>>(Ain, nullptr, Fin, WThi, WTlo, Fin,
                B640, QKV, nullptr, nullptr, N, 640, Fin, 0, nullptr, nullptr, nullptr);
        else
            gemm_planes<0><<<qg, 256, 0, stream>>>(Ain, AinLo, Fin, WThi, WTlo, Fin,
                B640, QKV, nullptr, nullptr, N, 640, Fin, 0, nullptr, nullptr, nullptr);

        node_attn_kernel<<<(N * 2 + 3) / 4, 256, 0, stream>>>(
            QKV, off0, ss0, off1, ss1, prel, ACChi, ACClo, N);

        transpose128p<<<64, 256, 0, stream>>>(Wa, WaThi, WaTlo);
        dim3 og(1, (N + GBM - 1) / GBM);
        gemm_planes<0><<<og, 256, 0, stream>>>(ACChi, ACClo, 128, WaThi, WaTlo, 128,
            ba, nullptr, outHi, outLo, N, 128, 128,
            gate ? 3 : 2, gate, skipHi, skipLo);
    };

    // layer 1 (f32 x input, no skip) -> H1 planes
    run_layer(x, nullptr, 1, F, W_k1, b_k1, W_q1, b_q1, W_v1, b_v1,
              a_rel1, m_rel1, p_rel1, W_a1, b_a1,
              nullptr, nullptr, nullptr, H1hi, H1lo);
    // layer 2 (H1 planes, gated skip from H1) -> H2 planes
    run_layer(H1hi, H1lo, 0, HDIM, W_k23, b_k23, W_q23, b_q23, W_v23, b_v23,
              a_rel23, m_rel23, p_rel23, W_a23, b_a23,
              skip23, H1hi, H1lo, H2hi, H2lo);
    // layer 3 (H2 planes, gated skip from H2) -> H1 planes (reuse)
    run_layer(H2hi, H2lo, 0, HDIM, W_k23 + 16384, b_k23 + 128, W_q23 + 16384, b_q23 + 128,
              W_v23 + 16384, b_v23 + 128, a_rel23 + 16384, m_rel23 + 16384,
              p_rel23 + 4, W_a23 + 16384, b_a23 + 128,
              skip23 + 1, H2hi, H2lo, H1hi, H1lo);

    // global mean pool (batch sorted)
    hipMemsetAsync(S, 0, (size_t)N_GRAPHS_C * HDIM * sizeof(float), stream);
    dim3 pg(N_GRAPHS_C, 8);
    pool_kernel<<<pg, HDIM, 0, stream>>>(H1hi, H1lo, batch, S, N);
    pool_finalize<<<N_GRAPHS_C, HDIM, 0, stream>>>(S, batch, GM, N);

    // MLP
    {
        dim3 g1(128 / BN, 1);
        gemm_bias_kernel<<<g1, 256, 0, stream>>>(GM, 128, W_m1, 128, b_m1, M1, 128,
                                                 N_GRAPHS_C, 128, 1);
        dim3 g2(256 / BN, 1);
        gemm_bias_kernel<<<g2, 256, 0, stream>>>(M1, 128, W_m2, 256, b_m2,
                                                 (float*)d_out, 256, N_GRAPHS_C, 128, 0);
    }
}

// Round 8
// 1007.531 us; speedup vs baseline: 2.9539x; 1.1137x over previous
//
#include <hip/hip_runtime.h>
#include <math.h>

#define N_NODES_C 50000
#define N_GRAPHS_C 64
#define HDIM 128

typedef short bf16x8 __attribute__((ext_vector_type(8)));
typedef short shortx4 __attribute__((ext_vector_type(4)));
typedef float floatx4 __attribute__((ext_vector_type(4)));

// split f32 -> hi (truncated bf16) + lo (bf16 of exact residual)
__device__ __forceinline__ void cvt_pair(float x, short& h, short& l) {
    union { float f; unsigned u; } a; a.f = x;
    h = (short)(a.u >> 16);
    union { unsigned u; float f; } b; b.u = a.u & 0xFFFF0000u;
    union { float f; unsigned u; } c; c.f = x - b.f;   // exact residual
    l = (short)(c.u >> 16);
}

__device__ __forceinline__ float b2f(short s) {
    union { unsigned u; float f; } x; x.u = ((unsigned)(unsigned short)s) << 16;
    return x.f;
}

// async global->LDS copy, 16 B per lane, LDS dest = wave-uniform base + lane*16
__device__ __forceinline__ void gld_lds16(const void* gsrc, void* ldst) {
    __builtin_amdgcn_global_load_lds(
        (const __attribute__((address_space(1))) unsigned int*)gsrc,
        (__attribute__((address_space(3))) unsigned int*)ldst,
        16, 0, 0);
}

// ============ MFMA GEMM with global_load_lds staging ============
// C[M,N] = A[M,K] @ BT[N,K]^T (+bias). A: f32 (AF32=1) or bf16 hi/lo planes.
// B: always bf16 hi/lo planes. Split-bf16 3-MFMA for f32-class accuracy.
// mode 0: Cf32 = v + bias          (ldc = Ntot)
// mode 2: planes = relu(v + bias)  (ldc = 128)
// mode 3: planes = relu(gate*v+bias' + (1-gate)*prev)  (ldc = 128)
#define GBM 128
#define GBN 128
#define GBK 32

template<int AF32>
__global__ __launch_bounds__(256, 2) void gemm_planes(
    const void* __restrict__ Aptr, const short* __restrict__ Alo, int lda,
    const short* __restrict__ Bhi, const short* __restrict__ Blo, int ldbt,
    const float* __restrict__ bias,
    float* __restrict__ Cf, short* __restrict__ Chi, short* __restrict__ Clo,
    int M, int Ntot, int K,
    int mode, const float* __restrict__ skipGate,
    const short* __restrict__ Phi, const short* __restrict__ Plo)
{
    __shared__ __align__(16) short AsH[AF32 ? (GBM * GBK * 2) : (GBM * GBK)];
    __shared__ __align__(16) short AsL[AF32 ? 8 : (GBM * GBK)];
    __shared__ __align__(16) short BsH[GBN * GBK];
    __shared__ __align__(16) short BsL[GBN * GBK];

    const int t = threadIdx.x;
    const int lane = t & 63;
    const int wave = t >> 6;
    const int wm = wave & 1, wn = wave >> 1;
    const int quad = lane >> 4, l15 = lane & 15;
    const long row0 = (long)blockIdx.y * GBM;
    const long col0 = (long)blockIdx.x * GBN;

    floatx4 acc[4][4];
    #pragma unroll
    for (int i = 0; i < 4; ++i)
        #pragma unroll
        for (int j = 0; j < 4; ++j)
            acc[i][j] = (floatx4){0.f, 0.f, 0.f, 0.f};

    for (int k0 = 0; k0 < K; k0 += GBK) {
        if (AF32) {
            // f32 tile 128x32 = 16 KB, 16 chunks of 1 KB (8 rows each).
            // XOR-swizzle granules so fragment ds_reads are ~conflict-free.
            const float* Af = (const float*)Aptr;
            int r8 = lane >> 3, kc8 = lane & 7;
            #pragma unroll
            for (int cc = 0; cc < 4; ++cc) {
                int ch = wave * 4 + cc;
                long gr = row0 + ch * 8 + r8;
                if (gr > M - 1) gr = M - 1;
                gld_lds16(Af + gr * lda + k0 + ((kc8 ^ r8) << 2),
                          (short*)AsH + ch * 512);
            }
        } else {
            const short* Ahi = (const short*)Aptr;
            int r16 = lane >> 2, g4 = lane & 3;
            #pragma unroll
            for (int cc = 0; cc < 2; ++cc) {
                int ch = wave * 2 + cc;
                long gr = row0 + ch * 16 + r16;
                if (gr > M - 1) gr = M - 1;
                long go = gr * lda + k0 + g4 * 8;
                gld_lds16(Ahi + go, AsH + ch * 512);
                gld_lds16(Alo + go, AsL + ch * 512);
            }
        }
        {
            int r16 = lane >> 2, g4 = lane & 3;
            #pragma unroll
            for (int cc = 0; cc < 2; ++cc) {
                int ch = wave * 2 + cc;
                long gc = col0 + ch * 16 + r16;
                if (gc > Ntot - 1) gc = Ntot - 1;
                long go = gc * ldbt + k0 + g4 * 8;
                gld_lds16(Bhi + go, BsH + ch * 512);
                gld_lds16(Blo + go, BsL + ch * 512);
            }
        }
        __syncthreads();   // compiler inserts vmcnt wait for global_load_lds

        bf16x8 aH[4], aL[4], bH[4], bL[4];
        if (AF32) {
            #pragma unroll
            for (int i = 0; i < 4; ++i) {
                int row = wm * 64 + i * 16 + l15;
                const float* fr = (const float*)AsH + row * 32;
                int x7 = row & 7;
                float4 f0 = *(const float4*)(fr + (((quad * 2)     ^ x7) << 2));
                float4 f1 = *(const float4*)(fr + (((quad * 2 + 1) ^ x7) << 2));
                short h0,h1,h2,h3,h4,h5,h6,h7, l0,l1,l2,l3,l4,l5,l6,l7;
                cvt_pair(f0.x,h0,l0); cvt_pair(f0.y,h1,l1);
                cvt_pair(f0.z,h2,l2); cvt_pair(f0.w,h3,l3);
                cvt_pair(f1.x,h4,l4); cvt_pair(f1.y,h5,l5);
                cvt_pair(f1.z,h6,l6); cvt_pair(f1.w,h7,l7);
                aH[i] = (bf16x8){h0,h1,h2,h3,h4,h5,h6,h7};
                aL[i] = (bf16x8){l0,l1,l2,l3,l4,l5,l6,l7};
            }
        } else {
            #pragma unroll
            for (int i = 0; i < 4; ++i) {
                int off = (wm * 64 + i * 16 + l15) * 32 + quad * 8;
                aH[i] = *(const bf16x8*)&AsH[off];
                aL[i] = *(const bf16x8*)&AsL[off];
            }
        }
        #pragma unroll
        for (int j = 0; j < 4; ++j) {
            int off = (wn * 64 + j * 16 + l15) * 32 + quad * 8;
            bH[j] = *(const bf16x8*)&BsH[off];
            bL[j] = *(const bf16x8*)&BsL[off];
        }
        #pragma unroll
        for (int i = 0; i < 4; ++i)
            #pragma unroll
            for (int j = 0; j < 4; ++j) {
                acc[i][j] = __builtin_amdgcn_mfma_f32_16x16x32_bf16(aH[i], bH[j], acc[i][j], 0, 0, 0);
                acc[i][j] = __builtin_amdgcn_mfma_f32_16x16x32_bf16(aH[i], bL[j], acc[i][j], 0, 0, 0);
                acc[i][j] = __builtin_amdgcn_mfma_f32_16x16x32_bf16(aL[i], bH[j], acc[i][j], 0, 0, 0);
            }
        __syncthreads();
    }

    float gate = 0.f;
    if (mode == 3) gate = 1.f / (1.f + __expf(-skipGate[0]));

    #pragma unroll
    for (int i = 0; i < 4; ++i) {
        #pragma unroll
        for (int rr = 0; rr < 4; ++rr) {
            long grow = row0 + wm * 64 + i * 16 + quad * 4 + rr;
            if (grow >= M) continue;
            #pragma unroll
            for (int j = 0; j < 4; ++j) {
                long gcol = col0 + wn * 64 + j * 16 + l15;
                if (gcol >= Ntot) continue;
                float v = acc[i][j][rr];
                if (bias) v += bias[gcol];
                if (mode == 0) {
                    Cf[grow * Ntot + gcol] = v;
                } else {
                    if (mode == 3) {
                        long po = grow * 128 + gcol;
                        float pv = b2f(Phi[po]) + b2f(Plo[po]);
                        v = gate * v + (1.f - gate) * pv;
                    }
                    v = fmaxf(v, 0.f);
                    short hh, ll; cvt_pair(v, hh, ll);
                    Chi[grow * 128 + gcol] = hh;
                    Clo[grow * 128 + gcol] = ll;
                }
            }
        }
    }
}

// ============ build fused WbigT[640, F] as bf16 hi/lo planes + bias640 ============
// cols: [0,128) q | [128,384) k_r | [384,640) v_r ; one c per blockIdx.y
__global__ __launch_bounds__(256) void build_wbigT_p(
    const float* __restrict__ Wq, const float* __restrict__ bq,
    const float* __restrict__ Wk, const float* __restrict__ bk,
    const float* __restrict__ Wv, const float* __restrict__ bv,
    const float* __restrict__ arel, const float* __restrict__ mrel,
    short* __restrict__ WThi, short* __restrict__ WTlo,
    float* __restrict__ bias, int F)
{
    __shared__ float Trow[64];
    int c = blockIdx.y;
    int f = blockIdx.x * 256 + threadIdx.x;
    float w = 0.f, b = 0.f;
    if (c < 128) {
        if (f < F) w = Wq[(long)f * 128 + c];
        b = bq[c];
    } else {
        int cc = c - 128;
        const float* Wsrc; const float* bsrc; const float* T;
        if (cc < 256) { Wsrc = Wk; bsrc = bk; T = arel; }
        else { cc -= 256; Wsrc = Wv; bsrc = bv; T = mrel; }
        int r = cc >> 7, j = cc & 127, h = j >> 6, e = j & 63;
        const float* Tr = T + (long)(r * 2 + h) * 4096 + e;
        if (threadIdx.x < 64) Trow[threadIdx.x] = Tr[(long)threadIdx.x * 64];
        __syncthreads();
        if (f < F) {
            const float* Wrow = Wsrc + (long)f * 128 + h * 64;
            float s = 0.f;
            #pragma unroll 4
            for (int d = 0; d < 64; ++d) s = fmaf(Wrow[d], Trow[d], s);
            w = s;
        }
        if (f == 0) {
            const float* brow = bsrc + h * 64;
            float sb = 0.f;
            for (int d = 0; d < 64; ++d) sb = fmaf(brow[d], Trow[d], sb);
            b = sb;
        }
    }
    if (f < F) {
        short hh, ll; cvt_pair(w, hh, ll);
        WThi[(long)c * F + f] = hh;
        WTlo[(long)c * F + f] = ll;
    }
    if (f == 0) bias[c] = b;
}

// W[128,128] -> WT planes [128,128] bf16 hi/lo
__global__ void transpose128p(const float* __restrict__ W,
                              short* __restrict__ hi, short* __restrict__ lo)
{
    int idx = blockIdx.x * 256 + threadIdx.x;   // 16384
    int c = idx >> 7, f = idx & 127;
    short hh, ll; cvt_pair(W[f * 128 + c], hh, ll);
    hi[idx] = hh; lo[idx] = ll;
}

// ============ CSR build, both relations per launch (blockIdx.y = r) ============
__global__ void csr_count2(const int* __restrict__ e0p, const int* __restrict__ e1p,
                           int* __restrict__ counts, int E, int N)
{
    int e = blockIdx.x * 256 + threadIdx.x;
    int r = blockIdx.y;
    const int* dst = (r ? e1p : e0p) + E;
    if (e < E) atomicAdd(&counts[r * N + dst[e]], 1);
}

__global__ __launch_bounds__(1024) void csr_scan2(
    const int* __restrict__ counts,
    int* __restrict__ off0, int* __restrict__ off1,
    int* __restrict__ cursor, int N, int E)
{
    __shared__ int part[1024];
    int r = blockIdx.x;
    const int* cnt = counts + (long)r * N;
    int* offs = r ? off1 : off0;
    int* cur  = cursor + (long)r * N;
    int t = threadIdx.x;
    int chunk = (N + 1023) / 1024;
    int a = t * chunk, b = a + chunk; if (b > N) b = N;
    int s = 0;
    for (int i = a; i < b; ++i) s += cnt[i];
    part[t] = s;
    __syncthreads();
    for (int off = 1; off < 1024; off <<= 1) {
        int v = (t >= off) ? part[t - off] : 0;
        __syncthreads();
        if (t >= off) part[t] += v;
        __syncthreads();
    }
    int p = (t == 0) ? 0 : part[t - 1];
    for (int i = a; i < b; ++i) {
        offs[i] = p; cur[i] = p; p += cnt[i];
    }
    if (t == 1023) offs[N] = E;
}

__global__ void csr_fill2(const int* __restrict__ e0p, const int* __restrict__ e1p,
                          int* __restrict__ cursor,
                          int* __restrict__ ss0, int* __restrict__ ss1, int E, int N)
{
    int e = blockIdx.x * 256 + threadIdx.x;
    if (e >= E) return;
    int r = blockIdx.y;
    const int* ed = r ? e1p : e0p;
    int* ss = r ? ss1 : ss0;
    int pos = atomicAdd(&cursor[r * N + ed[E + e]], 1);
    ss[pos] = ed[e];
}

// ============ node attention: one wave per (node, head) ============
// 16 lanes per edge, float4 gathers, BOTH relations interleaved in one loop
// (2x memory-level parallelism on the latency chain), masked (not clamped)
// out-of-range edges. No atomics. Writes ACC hi/lo planes.
__global__ __launch_bounds__(256) void node_attn_kernel(
    const float* __restrict__ qkv,
    const int* __restrict__ off0, const int* __restrict__ ss0,
    const int* __restrict__ off1, const int* __restrict__ ss1,
    const float* __restrict__ prel,     // [2][2] (r,h)
    short* __restrict__ ohi, short* __restrict__ olo, int N)
{
    int wid = blockIdx.x * 4 + (threadIdx.x >> 6);
    int lane = threadIdx.x & 63;
    int d = wid >> 1, h = wid & 1;
    if (d >= N) return;
    int g = lane >> 4, l = lane & 15;

    float4 q4 = *(const float4*)(qkv + (long)d * 640 + h * 64 + l * 4);

    int c0 = off0[d], b0 = off0[d + 1];
    int c1 = off1[d], b1 = off1[d + 1];
    const float* kp0 = qkv + 128 + h * 64 + l * 4;
    const float* vp0 = qkv + 384 + h * 64 + l * 4;
    const float* kp1 = kp0 + 128;
    const float* vp1 = vp0 + 128;
    float pr0 = prel[h] * 0.125f;       // includes 1/sqrt(64)
    float pr1 = prel[2 + h] * 0.125f;

    const float4 fz = {0.f, 0.f, 0.f, 0.f};
    float4 num0 = fz, num1 = fz;
    float den0 = 0.f, den1 = 0.f;

    while (c0 < b0 || c1 < b1) {
        // issue all gathers for both relations first (overlapped latency)
        float4 k0 = fz, v0 = fz, k1 = fz, v1 = fz;
        bool a0 = (c0 < b0) && (c0 + g < b0);
        bool a1 = (c1 < b1) && (c1 + g < b1);
        if (a0) {
            long so = (long)ss0[c0 + g] * 640;
            k0 = *(const float4*)(kp0 + so);
            v0 = *(const float4*)(vp0 + so);
        }
        if (a1) {
            long so = (long)ss1[c1 + g] * 640;
            k1 = *(const float4*)(kp1 + so);
            v1 = *(const float4*)(vp1 + so);
        }
        if (c0 < b0) {
            float p = q4.x*k0.x + q4.y*k0.y + q4.z*k0.z + q4.w*k0.w;
            p += __shfl_xor(p, 1, 16);
            p += __shfl_xor(p, 2, 16);
            p += __shfl_xor(p, 4, 16);
            p += __shfl_xor(p, 8, 16);
            float w = a0 ? __expf(p * pr0) : 0.f;
            den0 += w;
            num0.x = fmaf(w, v0.x, num0.x);
            num0.y = fmaf(w, v0.y, num0.y);
            num0.z = fmaf(w, v0.z, num0.z);
            num0.w = fmaf(w, v0.w, num0.w);
            c0 += 4;
        }
        if (c1 < b1) {
            float p = q4.x*k1.x + q4.y*k1.y + q4.z*k1.z + q4.w*k1.w;
            p += __shfl_xor(p, 1, 16);
            p += __shfl_xor(p, 2, 16);
            p += __shfl_xor(p, 4, 16);
            p += __shfl_xor(p, 8, 16);
            float w = a1 ? __expf(p * pr1) : 0.f;
            den1 += w;
            num1.x = fmaf(w, v1.x, num1.x);
            num1.y = fmaf(w, v1.y, num1.y);
            num1.z = fmaf(w, v1.z, num1.z);
            num1.w = fmaf(w, v1.w, num1.w);
            c1 += 4;
        }
    }

    // combine the 4 edge groups (butterfly over lanes 16,32)
    #pragma unroll
    for (int o = 16; o <= 32; o <<= 1) {
        num0.x += __shfl_xor(num0.x, o, 64); num0.y += __shfl_xor(num0.y, o, 64);
        num0.z += __shfl_xor(num0.z, o, 64); num0.w += __shfl_xor(num0.w, o, 64);
        den0   += __shfl_xor(den0,   o, 64);
        num1.x += __shfl_xor(num1.x, o, 64); num1.y += __shfl_xor(num1.y, o, 64);
        num1.z += __shfl_xor(num1.z, o, 64); num1.w += __shfl_xor(num1.w, o, 64);
        den1   += __shfl_xor(den1,   o, 64);
    }
    float inv0 = 1.f / (den0 + 1e-16f);
    float inv1 = 1.f / (den1 + 1e-16f);
    float4 accv;
    accv.x = num0.x * inv0 + num1.x * inv1;
    accv.y = num0.y * inv0 + num1.y * inv1;
    accv.z = num0.z * inv0 + num1.z * inv1;
    accv.w = num0.w * inv0 + num1.w * inv1;

    if (g == 0) {
        const float is2 = 0.70710678118654752f;
        float o0 = 0.5f * accv.x * (1.f + erff(accv.x * is2));
        float o1 = 0.5f * accv.y * (1.f + erff(accv.y * is2));
        float o2 = 0.5f * accv.z * (1.f + erff(accv.z * is2));
        float o3 = 0.5f * accv.w * (1.f + erff(accv.w * is2));
        short h0,h1,h2,h3, l0,l1,l2,l3;
        cvt_pair(o0,h0,l0); cvt_pair(o1,h1,l1);
        cvt_pair(o2,h2,l2); cvt_pair(o3,h3,l3);
        long oo = (long)d * 128 + h * 64 + l * 4;
        *(shortx4*)(ohi + oo) = (shortx4){h0,h1,h2,h3};
        *(shortx4*)(olo + oo) = (shortx4){l0,l1,l2,l3};
    }
}

// ============ f32 vector GEMM kept for tiny MLP ============
#define BM 64
#define BN 64
#define BK 16
__global__ __launch_bounds__(256) void gemm_bias_kernel(
    const float* __restrict__ A, int lda,
    const float* __restrict__ B, int ldb,
    const float* __restrict__ bias,
    float* __restrict__ C, int ldc,
    int M, int K, int epilogue)
{
    __shared__ float As[BK][BM + 4];
    __shared__ float Bs[BK][BN + 4];
    const int t = threadIdx.x;
    const int row0 = blockIdx.y * BM;
    const int col0 = blockIdx.x * BN;
    const int tm = (t >> 4) << 2;
    const int tn = (t & 15) << 2;
    float acc[4][4] = {};
    for (int k0 = 0; k0 < K; k0 += BK) {
        #pragma unroll
        for (int i = 0; i < 4; ++i) {
            int idx = t + i * 256;
            int m = idx >> 4, kk = idx & 15;
            int gm = row0 + m;
            As[kk][m] = (gm < M) ? A[(long)gm * lda + (k0 + kk)] : 0.f;
        }
        #pragma unroll
        for (int i = 0; i < 4; ++i) {
            int idx = t + i * 256;
            int kk = idx >> 6, n = idx & 63;
            Bs[kk][n] = B[(long)(k0 + kk) * ldb + (col0 + n)];
        }
        __syncthreads();
        #pragma unroll
        for (int kk = 0; kk < BK; ++kk) {
            float a[4], b[4];
            #pragma unroll
            for (int i = 0; i < 4; ++i) a[i] = As[kk][tm + i];
            #pragma unroll
            for (int j = 0; j < 4; ++j) b[j] = Bs[kk][tn + j];
            #pragma unroll
            for (int i = 0; i < 4; ++i)
                #pragma unroll
                for (int j = 0; j < 4; ++j)
                    acc[i][j] = fmaf(a[i], b[j], acc[i][j]);
        }
        __syncthreads();
    }
    #pragma unroll
    for (int i = 0; i < 4; ++i) {
        int gm = row0 + tm + i;
        if (gm >= M) continue;
        #pragma unroll
        for (int j = 0; j < 4; ++j) {
            int gn = col0 + tn + j;
            float v = acc[i][j];
            if (bias) v += bias[gn];
            if (epilogue >= 1) v = fmaxf(v, 0.f);
            C[(long)gm * ldc + gn] = v;
        }
    }
}

// ============ pooling (reads bf16 hi/lo planes) ============
__device__ inline int lower_bound_i(const int* __restrict__ a, int n, int v)
{
    int lo = 0, hi = n;
    while (lo < hi) { int mid = (lo + hi) >> 1; if (a[mid] < v) lo = mid + 1; else hi = mid; }
    return lo;
}

__global__ void pool_kernel(const short* __restrict__ hhi, const short* __restrict__ hlo,
                            const int* __restrict__ batch,
                            float* __restrict__ s, int N)
{
    int g = blockIdx.x, part = blockIdx.y, c = threadIdx.x;
    int start = lower_bound_i(batch, N, g);
    int end = lower_bound_i(batch, N, g + 1);
    int cnt = end - start, parts = gridDim.y;
    int chunk = (cnt + parts - 1) / parts;
    int a = start + part * chunk;
    int b = a + chunk; if (b > end) b = end;
    if (a >= b) return;
    float sum = 0.f;
    for (int n = a; n < b; ++n) {
        long o = (long)n * HDIM + c;
        sum += b2f(hhi[o]) + b2f(hlo[o]);
    }
    atomicAdd(&s[g * HDIM + c], sum);
}

__global__ void pool_finalize(const float* __restrict__ s, const int* __restrict__ batch,
                              float* __restrict__ g_out, int N)
{
    int g = blockIdx.x, c = threadIdx.x;
    int start = lower_bound_i(batch, N, g);
    int end = lower_bound_i(batch, N, g + 1);
    float cnt = (float)((end - start) > 1 ? (end - start) : 1);
    g_out[g * HDIM + c] = s[g * HDIM + c] / cnt;
}

// ============ host ============
extern "C" void kernel_launch(void* const* d_in, const int* in_sizes, int n_in,
                              void* d_out, int out_size, void* d_ws, size_t ws_size,
                              hipStream_t stream)
{
    const float* x      = (const float*)d_in[0];
    const int*   e0     = (const int*)d_in[1];
    const int*   e1     = (const int*)d_in[2];
    const int*   batch  = (const int*)d_in[3];
    const float* W_k1   = (const float*)d_in[4];
    const float* W_q1   = (const float*)d_in[5];
    const float* W_v1   = (const float*)d_in[6];
    const float* a_rel1 = (const float*)d_in[7];
    const float* m_rel1 = (const float*)d_in[8];
    const float* W_a1   = (const float*)d_in[9];
    const float* W_k23  = (const float*)d_in[10];
    const float* W_q23  = (const float*)d_in[11];
    const float* W_v23  = (const float*)d_in[12];
    const float* a_rel23= (const float*)d_in[13];
    const float* m_rel23= (const float*)d_in[14];
    const float* W_a23  = (const float*)d_in[15];
    const float* W_m1   = (const float*)d_in[16];
    const float* W_m2   = (const float*)d_in[17];
    const float* b_k1   = (const float*)d_in[18];
    const float* b_q1   = (const float*)d_in[19];
    const float* b_v1   = (const float*)d_in[20];
    const float* b_a1   = (const float*)d_in[21];
    const float* b_k23  = (const float*)d_in[22];
    const float* b_q23  = (const float*)d_in[23];
    const float* b_v23  = (const float*)d_in[24];
    const float* b_a23  = (const float*)d_in[25];
    const float* skip23 = (const float*)d_in[26];
    const float* b_m1   = (const float*)d_in[27];
    const float* b_m2   = (const float*)d_in[28];
    const float* p_rel1 = (const float*)d_in[29];
    const float* p_rel23= (const float*)d_in[30];

    const int N = N_NODES_C;
    const int E = in_sizes[1] / 2;
    const int F = in_sizes[0] / N;            // 512
    const long NP = (long)N * HDIM;           // 6.4M plane elements

    // ---- workspace layout ----
    float* ws    = (float*)d_ws;
    float* QKV   = ws;                                  // N*640 f32 (128 MB)
    short* ACChi = (short*)(QKV + (long)N * 640);       // 6 planes, 12.8 MB each
    short* ACClo = ACChi + NP;
    short* H1hi  = ACClo + NP;
    short* H1lo  = H1hi + NP;
    short* H2hi  = H1lo + NP;
    short* H2lo  = H2hi + NP;
    short* WThi  = H2lo + NP;                           // 640*512 max
    short* WTlo  = WThi + 640 * 512;
    short* WaThi = WTlo + 640 * 512;                    // 128*128
    short* WaTlo = WaThi + 128 * 128;
    float* B640  = (float*)(WaTlo + 128 * 128);         // 640
    float* S     = B640 + 640;
    float* GM    = S + N_GRAPHS_C * HDIM;
    float* M1    = GM + N_GRAPHS_C * HDIM;
    int*   off0  = (int*)(M1 + N_GRAPHS_C * HDIM);      // N+1
    int*   ss0   = off0 + (N + 1);                      // E
    int*   off1  = ss0 + E;                             // N+1
    int*   ss1   = off1 + (N + 1);                      // E
    int*   counts = (int*)QKV;                          // 2N, alias: dead before QKV written
    int*   cursor = counts + 2 * N;                     // 2N
    size_t needed = (size_t)((char*)(ss1 + E) - (char*)d_ws);
    if (ws_size < needed) return;

    // ---- build CSR once, both relations per launch ----
    {
        int eb = (E + 255) / 256;
        hipMemsetAsync(counts, 0, (size_t)(2 * N) * sizeof(int), stream);
        dim3 cg(eb, 2);
        csr_count2<<<cg, 256, 0, stream>>>(e0, e1, counts, E, N);
        csr_scan2<<<2, 1024, 0, stream>>>(counts, off0, off1, cursor, N, E);
        csr_fill2<<<cg, 256, 0, stream>>>(e0, e1, cursor, ss0, ss1, E, N);
    }

    auto run_layer = [&](const void* Ain, const short* AinLo, int AF, int Fin,
                         const float* Wk, const float* bk,
                         const float* Wq, const float* bq,
                         const float* Wv, const float* bv,
                         const float* arel, const float* mrel, const float* prel,
                         const float* Wa, const float* ba,
                         const float* gate, const short* skipHi, const short* skipLo,
                         short* outHi, short* outLo) {
        dim3 bg((Fin + 255) / 256, 640);
        build_wbigT_p<<<bg, 256, 0, stream>>>(Wq, bq, Wk, bk, Wv, bv,
                                              arel, mrel, WThi, WTlo, B640, Fin);
        dim3 qg(640 / GBN, (N + GBM - 1) / GBM);
        if (AF)
            gemm_planes<1><<<qg, 256, 0, stream>>>(Ain, nullptr, Fin, WThi, WTlo, Fin,
                B640, QKV, nullptr, nullptr, N, 640, Fin, 0, nullptr, nullptr, nullptr);
        else
            gemm_planes<0><<<qg, 256, 0, stream>>>(Ain, AinLo, Fin, WThi, WTlo, Fin,
                B640, QKV, nullptr, nullptr, N, 640, Fin, 0, nullptr, nullptr, nullptr);

        node_attn_kernel<<<(N * 2 + 3) / 4, 256, 0, stream>>>(
            QKV, off0, ss0, off1, ss1, prel, ACChi, ACClo, N);

        transpose128p<<<64, 256, 0, stream>>>(Wa, WaThi, WaTlo);
        dim3 og(1, (N + GBM - 1) / GBM);
        gemm_planes<0><<<og, 256, 0, stream>>>(ACChi, ACClo, 128, WaThi, WaTlo, 128,
            ba, nullptr, outHi, outLo, N, 128, 128,
            gate ? 3 : 2, gate, skipHi, skipLo);
    };

    // layer 1 (f32 x input, no skip) -> H1 planes
    run_layer(x, nullptr, 1, F, W_k1, b_k1, W_q1, b_q1, W_v1, b_v1,
              a_rel1, m_rel1, p_rel1, W_a1, b_a1,
              nullptr, nullptr, nullptr, H1hi, H1lo);
    // layer 2 (H1 planes, gated skip from H1) -> H2 planes
    run_layer(H1hi, H1lo, 0, HDIM, W_k23, b_k23, W_q23, b_q23, W_v23, b_v23,
              a_rel23, m_rel23, p_rel23, W_a23, b_a23,
              skip23, H1hi, H1lo, H2hi, H2lo);
    // layer 3 (H2 planes, gated skip from H2) -> H1 planes (reuse)
    run_layer(H2hi, H2lo, 0, HDIM, W_k23 + 16384, b_k23 + 128, W_q23 + 16384, b_q23 + 128,
              W_v23 + 16384, b_v23 + 128, a_rel23 + 16384, m_rel23 + 16384,
              p_rel23 + 4, W_a23 + 16384, b_a23 + 128,
              skip23 + 1, H2hi, H2lo, H1hi, H1lo);

    // global mean pool (batch sorted)
    hipMemsetAsync(S, 0, (size_t)N_GRAPHS_C * HDIM * sizeof(float), stream);
    dim3 pg(N_GRAPHS_C, 8);
    pool_kernel<<<pg, HDIM, 0, stream>>>(H1hi, H1lo, batch, S, N);
    pool_finalize<<<N_GRAPHS_C, HDIM, 0, stream>>>(S, batch, GM, N);

    // MLP
    {
        dim3 g1(128 / BN, 1);
        gemm_bias_kernel<<<g1, 256, 0, stream>>>(GM, 128, W_m1, 128, b_m1, M1, 128,
                                                 N_GRAPHS_C, 128, 1);
        dim3 g2(256 / BN, 1);
        gemm_bias_kernel<<<g2, 256, 0, stream>>>(M1, 128, W_m2, 256, b_m2,
                                                 (float*)d_out, 256, N_GRAPHS_C, 128, 0);
    }
}